// Round 5
// baseline (6695.078 us; speedup 1.0000x reference)
//
#include <hip/hip_runtime.h>
#include <hip/hip_cooperative_groups.h>

namespace cg = cooperative_groups;

#define BB 64   // batch
#define CC 64   // channels

typedef __attribute__((ext_vector_type(8))) short short8;
typedef __attribute__((ext_vector_type(4))) short short4v;
typedef __attribute__((ext_vector_type(4))) float f32x4;

__device__ __forceinline__ float bf2f(unsigned short h) {
    unsigned int u = ((unsigned int)h) << 16;
    float f; __builtin_memcpy(&f, &u, 4); return f;
}
__device__ __forceinline__ unsigned short f2bf(float f) {
    unsigned int u; __builtin_memcpy(&u, &f, 4);
    u += 0x7fffu + ((u >> 16) & 1u);
    return (unsigned short)(u >> 16);
}

// ================= GN1 stats directly from x (recompute conv1) =================
__global__ __launch_bounds__(256) void conv1stats_kernel(const float* __restrict__ x,
    const float* __restrict__ w1, const float* __restrict__ b1,
    float* __restrict__ ps, float* __restrict__ ps2) {
    __shared__ float sw1[576];
    __shared__ float sb1[64];
    __shared__ float xs[10 * 130];
    int tid = threadIdx.x;
    int qq = blockIdx.x;
    int b = blockIdx.y;
    for (int i = tid; i < 576; i += 256) sw1[i] = w1[i];
    if (tid < 64) sb1[tid] = b1[tid];
    const float* xb = x + (size_t)b * 130 * 130;
    int c = tid >> 2, q = tid & 3;
    float s = 0.f, s2 = 0.f;
    for (int sidx = 0; sidx < 2; sidx++) {
        int row0 = (qq * 2 + sidx) * 8;
        __syncthreads();
        for (int i = tid; i < 1300; i += 256) xs[i] = xb[row0 * 130 + i];
        __syncthreads();
        const float* wc = &sw1[c * 9];
        float bc = sb1[c];
        for (int p = q; p < 1024; p += 4) {
            int y = p >> 7, xx = p & 127;
            float v = bc;
#pragma unroll
            for (int ky = 0; ky < 3; ky++)
#pragma unroll
                for (int kx = 0; kx < 3; kx++)
                    v += xs[(y + ky) * 130 + xx + kx] * wc[ky * 3 + kx];
            s += v; s2 += v * v;
        }
    }
    s  += __shfl_xor(s, 1, 64);  s  += __shfl_xor(s, 2, 64);
    s2 += __shfl_xor(s2, 1, 64); s2 += __shfl_xor(s2, 2, 64);
    if (q == 0) {
        ps [(b * 8 + qq) * 64 + c] = s;
        ps2[(b * 8 + qq) * 64 + c] = s2;
    }
}

__global__ __launch_bounds__(256) void gn1fin_kernel(const float* __restrict__ ps,
    const float* __restrict__ ps2, const float* __restrict__ n1w, const float* __restrict__ n1b,
    float* __restrict__ gn1sc, float* __restrict__ gn1sh) {
    int i = blockIdx.x * 256 + threadIdx.x;
    if (i >= BB * CC) return;
    int c = i & 63, b = i >> 6;
    float s = 0.f, s2 = 0.f;
#pragma unroll
    for (int qq = 0; qq < 8; qq++) {
        s  += ps [(b * 8 + qq) * 64 + c];
        s2 += ps2[(b * 8 + qq) * 64 + c];
    }
    float mean = s / 16384.f;
    float var = s2 / 16384.f - mean * mean;
    float rstd = rsqrtf(var + 1e-5f);
    float sc = rstd * n1w[c];
    gn1sc[i] = sc;
    gn1sh[i] = n1b[c] - mean * sc;
}

// ===== weight prepack, chunk-major A: Apk[kc][co][32] bf16 =====
// sets: 0=ode_w1 (18 chunks), 1=ode_w2 (18), 2=ds_w2 (32), 3=ds_w3 (32)
__global__ __launch_bounds__(256) void prepack_kernel(const float* __restrict__ w1,
    const float* __restrict__ w2, const float* __restrict__ dw2,
    const float* __restrict__ dw3, unsigned short* __restrict__ Apk,
    float* __restrict__ Stab) {
    int set = blockIdx.y, kc = blockIdx.x, tid = threadIdx.x;
    int nchunk = (set < 2) ? 18 : 32;
    if (kc < nchunk) {
        const float* w = (set == 0) ? w1 : (set == 1) ? w2 : (set == 2) ? dw2 : dw3;
        size_t off = (set == 0) ? 0 : (set == 1) ? 36864 : (set == 2) ? 73728 : 139264;
        for (int e = tid; e < 2048; e += 256) {
            int co = e >> 5, j = e & 31;
            int k = kc * 32 + j;
            int ci = k & 63;
            int tap = k >> 6;
            float val;
            if (set < 2) val = w[(co * 65 + ci + 1) * 9 + tap];
            else         val = w[((co << 6) + ci) * 16 + tap];
            Apk[off + (size_t)kc * 2048 + e] = f2bf(val);
        }
    }
    if (set < 2 && kc == 0) {
        const float* w = set ? w2 : w1;
        for (int t = tid; t < 576; t += 256) {
            int co = t / 9, tap = t % 9;
            Stab[set * 576 + t] = w[(co * 65) * 9 + tap];
        }
    }
}

// ===== ds2mfma: x -> conv1 -> GN1 -> ReLU (in-register) -> conv4x4/s2 MFMA -> h2 =====
__global__ __launch_bounds__(256) void ds2mfma_kernel(const float* __restrict__ x,
    const float* __restrict__ w1, const float* __restrict__ b1,
    const float* __restrict__ gn1sc, const float* __restrict__ gn1sh,
    const unsigned short* __restrict__ Apk, const float* __restrict__ bias2,
    unsigned short* __restrict__ h2, float* __restrict__ sums_out) {
    __shared__ unsigned short X[2 * 198 * 64];
    __shared__ float xs[8 * 68];
    __shared__ float sw1[576];
    __shared__ float sb1[64], ssc[64], ssh[64], sb2[64];
    __shared__ float sred[4][64], s2red[4][64];
    int tid = threadIdx.x;
    int b = blockIdx.y;
    int bx = blockIdx.x;
    int xh = bx & 1, sy = bx >> 1;
    int lane = tid & 63, w = tid >> 6;
    int colL = lane & 15, quad = lane >> 4;

    for (int i = tid; i < 576; i += 256) sw1[i] = w1[i];
    if (tid < 64) {
        sb1[tid] = b1[tid];
        ssc[tid] = gn1sc[b * 64 + tid];
        ssh[tid] = gn1sh[b * 64 + tid];
        sb2[tid] = bias2[tid];
    }
    {
        const float* xb = x + (size_t)b * 130 * 130;
        for (int i = tid; i < 544; i += 256) {
            int r = i / 68, cc = i % 68;
            int xr = 4 * sy - 1 + r, xcg = 64 * xh - 1 + cc;
            xs[i] = (xr >= 0 && xr < 130 && xcg >= 0 && xcg < 130) ? xb[xr * 130 + xcg] : 0.f;
        }
    }
    __syncthreads();
    {
        int sub = tid & 7;
        float sbr[8], scr[8], shr[8];
#pragma unroll
        for (int e = 0; e < 8; e++) {
            int c = sub * 8 + e;
            sbr[e] = sb1[c]; scr[e] = ssc[c]; shr[e] = ssh[c];
        }
        for (int i = tid; i < 3168; i += 256) {
            int pidx = i >> 3;
            int ir = pidx / 66, ic = pidx - ir * 66;
            int gy = 4 * sy - 1 + ir, gxg = 64 * xh - 1 + ic;
            short8 o;
            if (gy >= 0 && gy < 128 && gxg >= 0 && gxg < 128) {
#pragma unroll
                for (int e = 0; e < 8; e++) {
                    int c = sub * 8 + e;
                    float v = sbr[e];
#pragma unroll
                    for (int ky = 0; ky < 3; ky++)
#pragma unroll
                        for (int kx = 0; kx < 3; kx++)
                            v += xs[(ir + ky) * 68 + ic + kx] * sw1[c * 9 + ky * 3 + kx];
                    o[e] = (short)f2bf(fmaxf(fmaf(v, scr[e], shr[e]), 0.f));
                }
            } else {
#pragma unroll
                for (int e = 0; e < 8; e++) o[e] = 0;
            }
            int p = ic & 1;
            int psx = ir * 33 + (ic >> 1);
            *(short8*)(X + ((p * 198 + psx) << 6) + ((sub ^ (psx & 7)) << 3)) = o;
        }
    }
    __syncthreads();

    int l = w >> 1, oxb = (w & 1) * 16;
    int oxl = oxb + colL;
    f32x4 acc[4] = {};
    for (int kc = 0; kc < 32; ++kc) {
        int tap = kc >> 1;
        int ky = tap >> 2, kx = tap & 3;
        int chgrp = (kc & 1) * 4 + quad;
        int ir = 2 * l + ky;
        int p = kx & 1;
        int psx = ir * 33 + oxl + (kx >> 1);
        short8 bb = *(const short8*)(X + ((p * 198 + psx) << 6) + ((chgrp ^ (psx & 7)) << 3));
        const unsigned short* ap = Apk + (((kc << 6) + colL) << 5) + (quad << 3);
        short8 a0 = *(const short8*)(ap);
        short8 a1 = *(const short8*)(ap + 512);
        short8 a2 = *(const short8*)(ap + 1024);
        short8 a3 = *(const short8*)(ap + 1536);
        acc[0] = __builtin_amdgcn_mfma_f32_16x16x32_bf16(a0, bb, acc[0], 0, 0, 0);
        acc[1] = __builtin_amdgcn_mfma_f32_16x16x32_bf16(a1, bb, acc[1], 0, 0, 0);
        acc[2] = __builtin_amdgcn_mfma_f32_16x16x32_bf16(a2, bb, acc[2], 0, 0, 0);
        acc[3] = __builtin_amdgcn_mfma_f32_16x16x32_bf16(a3, bb, acc[3], 0, 0, 0);
    }

    float sl[16], s2l[16];
#pragma unroll
    for (int i = 0; i < 16; i++) { sl[i] = 0.f; s2l[i] = 0.f; }
    int oy = 2 * sy + l, oxg = xh * 32 + oxl;
#pragma unroll
    for (int mt = 0; mt < 4; ++mt) {
        int co0 = mt * 16 + quad * 4;
        size_t base = ((size_t)((b * 64 + oy) * 64 + oxg)) * 64 + co0;
        short4v o;
#pragma unroll
        for (int r = 0; r < 4; ++r) {
            unsigned short hh = f2bf(acc[mt][r] + sb2[co0 + r]);
            o[r] = (short)hh;
            float f = bf2f(hh);
            sl[mt * 4 + r] += f; s2l[mt * 4 + r] += f * f;
        }
        *(short4v*)(h2 + base) = o;
    }
#pragma unroll
    for (int idx = 0; idx < 16; ++idx) {
        float s = sl[idx], s2 = s2l[idx];
        s += __shfl_xor(s, 1, 64); s += __shfl_xor(s, 2, 64);
        s += __shfl_xor(s, 4, 64); s += __shfl_xor(s, 8, 64);
        s2 += __shfl_xor(s2, 1, 64); s2 += __shfl_xor(s2, 2, 64);
        s2 += __shfl_xor(s2, 4, 64); s2 += __shfl_xor(s2, 8, 64);
        if (colL == 0) {
            int co = (idx >> 2) * 16 + quad * 4 + (idx & 3);
            sred[w][co] = s; s2red[w][co] = s2;
        }
    }
    __syncthreads();
    if (tid < 64) {
        float s = sred[0][tid] + sred[1][tid] + sred[2][tid] + sred[3][tid];
        float s2 = s2red[0][tid] + s2red[1][tid] + s2red[2][tid] + s2red[3][tid];
        atomicAdd(&sums_out[b * 64 + tid], s);
        atomicAdd(&sums_out[4096 + b * 64 + tid], s2);
    }
}

// ===== ds3mfma: h2(bf16 NHWC) -> GN2+ReLU on load -> conv4x4/s2 MFMA -> z,zb,sums =====
__global__ __launch_bounds__(256) void ds3mfma_kernel(const unsigned short* __restrict__ h2,
    const float* __restrict__ sums_in, const float* __restrict__ gw, const float* __restrict__ gb,
    const unsigned short* __restrict__ Apk, const float* __restrict__ bias3,
    float* __restrict__ z, unsigned short* __restrict__ zb, float* __restrict__ sums_out) {
    __shared__ unsigned short X[2 * 198 * 64];
    __shared__ float ssc[64], ssh[64], sb3[64];
    __shared__ float sred[4][64], s2red[4][64];
    int tid = threadIdx.x;
    int b = blockIdx.y, sy = blockIdx.x;
    int lane = tid & 63, w = tid >> 6;
    int colL = lane & 15, quad = lane >> 4;

    if (tid < 64) {
        int c = tid;
        float s = sums_in[b * 64 + c];
        float s2 = sums_in[4096 + b * 64 + c];
        float mean = s * (1.f / 4096.f);
        float var = fmaxf(s2 * (1.f / 4096.f) - mean * mean, 0.f);
        float sc = rsqrtf(var + 1e-5f) * gw[c];
        ssc[c] = sc;
        ssh[c] = gb[c] - mean * sc;
        sb3[c] = bias3[c];
    }
    __syncthreads();
    {
        int sub = tid & 7;
        float scr[8], shr[8];
#pragma unroll
        for (int e = 0; e < 8; e++) { scr[e] = ssc[sub * 8 + e]; shr[e] = ssh[sub * 8 + e]; }
        for (int i = tid; i < 3168; i += 256) {
            int pidx = i >> 3;
            int ir = pidx / 66, ic = pidx - ir * 66;
            int gy = 4 * sy - 1 + ir, gx = ic - 1;
            short8 o;
            if (gy >= 0 && gy < 64 && gx >= 0 && gx < 64) {
                short8 d = *(const short8*)(h2 + ((size_t)((b * 64 + gy) * 64 + gx)) * 64 + sub * 8);
#pragma unroll
                for (int e = 0; e < 8; e++) {
                    float f = bf2f((unsigned short)d[e]);
                    o[e] = (short)f2bf(fmaxf(fmaf(f, scr[e], shr[e]), 0.f));
                }
            } else {
#pragma unroll
                for (int e = 0; e < 8; e++) o[e] = 0;
            }
            int p = ic & 1;
            int psx = ir * 33 + (ic >> 1);
            *(short8*)(X + ((p * 198 + psx) << 6) + ((sub ^ (psx & 7)) << 3)) = o;
        }
    }
    __syncthreads();

    int l = w >> 1, oxb = (w & 1) * 16;
    int oxl = oxb + colL;
    f32x4 acc[4] = {};
    for (int kc = 0; kc < 32; ++kc) {
        int tap = kc >> 1;
        int ky = tap >> 2, kx = tap & 3;
        int chgrp = (kc & 1) * 4 + quad;
        int ir = 2 * l + ky;
        int p = kx & 1;
        int psx = ir * 33 + oxl + (kx >> 1);
        short8 bb = *(const short8*)(X + ((p * 198 + psx) << 6) + ((chgrp ^ (psx & 7)) << 3));
        const unsigned short* ap = Apk + (((kc << 6) + colL) << 5) + (quad << 3);
        short8 a0 = *(const short8*)(ap);
        short8 a1 = *(const short8*)(ap + 512);
        short8 a2 = *(const short8*)(ap + 1024);
        short8 a3 = *(const short8*)(ap + 1536);
        acc[0] = __builtin_amdgcn_mfma_f32_16x16x32_bf16(a0, bb, acc[0], 0, 0, 0);
        acc[1] = __builtin_amdgcn_mfma_f32_16x16x32_bf16(a1, bb, acc[1], 0, 0, 0);
        acc[2] = __builtin_amdgcn_mfma_f32_16x16x32_bf16(a2, bb, acc[2], 0, 0, 0);
        acc[3] = __builtin_amdgcn_mfma_f32_16x16x32_bf16(a3, bb, acc[3], 0, 0, 0);
    }

    float sl[16], s2l[16];
#pragma unroll
    for (int i = 0; i < 16; i++) { sl[i] = 0.f; s2l[i] = 0.f; }
    int py = 2 * sy + l;
#pragma unroll
    for (int mt = 0; mt < 4; ++mt) {
        int co0 = mt * 16 + quad * 4;
        size_t base = ((size_t)((b << 10) + py * 32 + oxl)) * 64 + co0;
        f32x4 zv;
        short4v o;
#pragma unroll
        for (int r = 0; r < 4; ++r) {
            float val = acc[mt][r] + sb3[co0 + r];
            zv[r] = val;
            unsigned short hh = f2bf(val);
            o[r] = (short)hh;
            float f = bf2f(hh);
            sl[mt * 4 + r] += f; s2l[mt * 4 + r] += f * f;
        }
        *(f32x4*)(z + base) = zv;
        *(short4v*)(zb + base) = o;
    }
#pragma unroll
    for (int idx = 0; idx < 16; ++idx) {
        float s = sl[idx], s2 = s2l[idx];
        s += __shfl_xor(s, 1, 64); s += __shfl_xor(s, 2, 64);
        s += __shfl_xor(s, 4, 64); s += __shfl_xor(s, 8, 64);
        s2 += __shfl_xor(s2, 1, 64); s2 += __shfl_xor(s2, 2, 64);
        s2 += __shfl_xor(s2, 4, 64); s2 += __shfl_xor(s2, 8, 64);
        if (colL == 0) {
            int co = (idx >> 2) * 16 + quad * 4 + (idx & 3);
            sred[w][co] = s; s2red[w][co] = s2;
        }
    }
    __syncthreads();
    if (tid < 64) {
        float s = sred[0][tid] + sred[1][tid] + sred[2][tid] + sred[3][tid];
        float s2 = s2red[0][tid] + s2red[1][tid] + s2red[2][tid] + s2red[3][tid];
        atomicAdd(&sums_out[b * 64 + tid], s);
        atomicAdd(&sums_out[4096 + b * 64 + tid], s2);
    }
}

// ==================== persistent cooperative ODE kernel ====================
// grid (8 strips of 4 rows, 64 samples) x 512 threads. z & kacc live in registers
// for all 10 RK4 steps; activations round-trip via bf16 NHWC buffers + grid.sync.
__global__ __launch_bounds__(512, 4) void ode_coop_kernel(
    float* __restrict__ z, unsigned short* __restrict__ zb,
    unsigned short* __restrict__ u, unsigned short* __restrict__ v,
    const float* __restrict__ sums0,
    float* __restrict__ psA, float* __restrict__ psB,
    const unsigned short* __restrict__ AP1, const unsigned short* __restrict__ AP2,
    const float* __restrict__ Stab,
    const float* __restrict__ ob1, const float* __restrict__ ob2,
    const float* __restrict__ n1w, const float* __restrict__ n1b,
    const float* __restrict__ n2w, const float* __restrict__ n2b)
{
    cg::grid_group grid = cg::this_grid();
    __shared__ unsigned short X[6 * 34 * 64];
    __shared__ float ssc[64], ssh[64];
    __shared__ float tS[64], trow0[64], trow2[64], tcol0[64], tcol2[64];
    __shared__ float tc00[64], tc02[64], tc20[64], tc22[64];
    __shared__ float sred[8][64], s2red[8][64];

    const int tid = threadIdx.x;
    const int b = blockIdx.y, strip = blockIdx.x;
    const int y0 = strip * 4;
    const int lane = tid & 63, w = tid >> 6;
    const int colL = lane & 15, quad = lane >> 4;
    const int l = w >> 1, oxb = (w & 1) * 16;
    const int px = oxb + colL;
    const int py = y0 + l;
    const bool by0 = (py == 0), by1 = (py == 31);
    const bool bx0 = (px == 0), bx1 = (px == 31);

    const size_t zbase = ((size_t)((b << 10) + py * 32 + px)) * 64 + quad * 4;
    f32x4 zr[4], kr[4];
#pragma unroll
    for (int mt = 0; mt < 4; ++mt) { zr[mt] = *(const f32x4*)(z + zbase + mt * 16); kr[mt] = 0.f; }

#pragma unroll 1
    for (int p = 0; p < 80; ++p) {
        const int stepi = p >> 3, sub = p & 7;
        const int stage = sub >> 1;
        const bool isA = (sub & 1) == 0;
        const float tt = 0.1f * (float)stepi
                       + ((stage == 0) ? 0.f : (stage == 3) ? 0.1f : 0.05f);
        const unsigned short* in = isA ? ((stage == 0) ? zb : u) : v;
        unsigned short* out = isA ? v : ((stage == 3) ? zb : u);
        const unsigned short* Apk = isA ? AP1 : AP2;
        const float* st = isA ? Stab : (Stab + 576);
        const float* bias = isA ? ob1 : ob2;
        const float* gw = isA ? n1w : n2w;
        const float* gb = isA ? n1b : n2b;
        const int mode = isA ? 3 : ((stage == 0) ? 0 : (stage == 3) ? 2 : 1);
        const float aa = (stage <= 1) ? 0.05f : (stage == 2) ? 0.1f : (0.1f / 6.0f);

        grid.sync();

        // stats finalize + t-channel tables
        if (tid < 64) {
            float s, s2;
            if (p == 0) {
                s = sums0[b * 64 + tid];
                s2 = sums0[4096 + b * 64 + tid];
            } else {
                const float* P = ((p - 1) & 1) ? psB : psA;
                const float* q = P + (size_t)b * 1024 + tid;
                s = 0.f; s2 = 0.f;
#pragma unroll
                for (int i = 0; i < 8; i++) { s += q[i * 128]; s2 += q[i * 128 + 64]; }
            }
            float mean = s * (1.f / 1024.f);
            float var = fmaxf(s2 * (1.f / 1024.f) - mean * mean, 0.f);
            float sc = rsqrtf(var + 1e-5f) * gw[tid];
            ssc[tid] = sc;
            ssh[tid] = gb[tid] - mean * sc;
        } else if (tid < 128) {
            int co = tid - 64;
            float w0[9];
#pragma unroll
            for (int k = 0; k < 9; k++) w0[k] = st[co * 9 + k] * tt;
            tS[co] = bias[co] + w0[0]+w0[1]+w0[2]+w0[3]+w0[4]+w0[5]+w0[6]+w0[7]+w0[8];
            trow0[co] = w0[0] + w0[1] + w0[2];
            trow2[co] = w0[6] + w0[7] + w0[8];
            tcol0[co] = w0[0] + w0[3] + w0[6];
            tcol2[co] = w0[2] + w0[5] + w0[8];
            tc00[co] = w0[0]; tc02[co] = w0[2]; tc20[co] = w0[6]; tc22[co] = w0[8];
        }
        __syncthreads();

        // stage 6 rows x 34 cols x 64 ch (GN+ReLU fused, zero-pad inline)
        for (int i = tid; i < 1632; i += 512) {
            int sub8 = i & 7, pidx = i >> 3;
            int r = pidx / 34, cc = pidx - r * 34;
            int gy = y0 - 1 + r, gx = cc - 1;
            short8 o;
            if (gy >= 0 && gy < 32 && gx >= 0 && gx < 32) {
                short8 d = *(const short8*)(in + ((size_t)((b << 10) + gy * 32 + gx)) * 64 + sub8 * 8);
#pragma unroll
                for (int e = 0; e < 8; e++) {
                    float f = bf2f((unsigned short)d[e]);
                    o[e] = (short)f2bf(fmaxf(fmaf(f, ssc[sub8 * 8 + e], ssh[sub8 * 8 + e]), 0.f));
                }
            } else {
#pragma unroll
                for (int e = 0; e < 8; e++) o[e] = 0;
            }
            int psx = r * 34 + cc;
            *(short8*)(X + (psx << 6) + ((sub8 ^ (psx & 7)) << 3)) = o;
        }
        __syncthreads();

        // K-loop: 18 chunks of 32
        f32x4 acc[4] = {};
#pragma unroll
        for (int kc = 0; kc < 18; ++kc) {
            int tap = kc >> 1;
            int dy = tap / 3, dx = tap % 3;
            int chgrp = (kc & 1) * 4 + quad;
            int psx = (l + dy) * 34 + px + dx;
            short8 bb = *(const short8*)(X + (psx << 6) + ((chgrp ^ (psx & 7)) << 3));
            const unsigned short* ap = Apk + (((kc << 6) + colL) << 5) + (quad << 3);
            short8 a0 = *(const short8*)(ap);
            short8 a1 = *(const short8*)(ap + 512);
            short8 a2 = *(const short8*)(ap + 1024);
            short8 a3 = *(const short8*)(ap + 1536);
            acc[0] = __builtin_amdgcn_mfma_f32_16x16x32_bf16(a0, bb, acc[0], 0, 0, 0);
            acc[1] = __builtin_amdgcn_mfma_f32_16x16x32_bf16(a1, bb, acc[1], 0, 0, 0);
            acc[2] = __builtin_amdgcn_mfma_f32_16x16x32_bf16(a2, bb, acc[2], 0, 0, 0);
            acc[3] = __builtin_amdgcn_mfma_f32_16x16x32_bf16(a3, bb, acc[3], 0, 0, 0);
        }

        // epilogue: t-channel correction, register RK4 state update, out + stats
        float sl[16], s2l[16];
#pragma unroll
        for (int i = 0; i < 16; i++) { sl[i] = 0.f; s2l[i] = 0.f; }
#pragma unroll
        for (int mt = 0; mt < 4; ++mt) {
            int co0 = mt * 16 + quad * 4;
            float vout[4];
#pragma unroll
            for (int r = 0; r < 4; ++r) {
                int co = co0 + r;
                float val = acc[mt][r] + tS[co];
                if (by0) { val -= trow0[co]; if (bx0) val += tc00[co]; if (bx1) val += tc02[co]; }
                if (by1) { val -= trow2[co]; if (bx0) val += tc20[co]; if (bx1) val += tc22[co]; }
                if (bx0) val -= tcol0[co];
                if (bx1) val -= tcol2[co];
                vout[r] = val;
            }
            short4v o;
            if (mode == 3) {
#pragma unroll
                for (int r = 0; r < 4; ++r) {
                    unsigned short hh = f2bf(vout[r]);
                    o[r] = (short)hh;
                    float f = bf2f(hh);
                    sl[mt * 4 + r] += f; s2l[mt * 4 + r] += f * f;
                }
            } else if (mode == 0) {
#pragma unroll
                for (int r = 0; r < 4; ++r) {
                    kr[mt][r] = vout[r];
                    unsigned short hh = f2bf(zr[mt][r] + aa * vout[r]);
                    o[r] = (short)hh;
                    float f = bf2f(hh);
                    sl[mt * 4 + r] += f; s2l[mt * 4 + r] += f * f;
                }
            } else if (mode == 1) {
#pragma unroll
                for (int r = 0; r < 4; ++r) {
                    kr[mt][r] += 2.f * vout[r];
                    unsigned short hh = f2bf(zr[mt][r] + aa * vout[r]);
                    o[r] = (short)hh;
                    float f = bf2f(hh);
                    sl[mt * 4 + r] += f; s2l[mt * 4 + r] += f * f;
                }
            } else { // mode 2: z += c6*(kacc + k4)
#pragma unroll
                for (int r = 0; r < 4; ++r) {
                    float zn = zr[mt][r] + aa * (kr[mt][r] + vout[r]);
                    zr[mt][r] = zn;
                    unsigned short hh = f2bf(zn);
                    o[r] = (short)hh;
                    float f = bf2f(hh);
                    sl[mt * 4 + r] += f; s2l[mt * 4 + r] += f * f;
                }
            }
            *(short4v*)(out + zbase + mt * 16) = o;
        }
#pragma unroll
        for (int idx = 0; idx < 16; ++idx) {
            float s = sl[idx], s2 = s2l[idx];
            s += __shfl_xor(s, 1, 64); s += __shfl_xor(s, 2, 64);
            s += __shfl_xor(s, 4, 64); s += __shfl_xor(s, 8, 64);
            s2 += __shfl_xor(s2, 1, 64); s2 += __shfl_xor(s2, 2, 64);
            s2 += __shfl_xor(s2, 4, 64); s2 += __shfl_xor(s2, 8, 64);
            if (colL == 0) {
                int co = (idx >> 2) * 16 + quad * 4 + (idx & 3);
                sred[w][co] = s; s2red[w][co] = s2;
            }
        }
        __syncthreads();
        if (tid < 64) {
            float s = 0.f, s2 = 0.f;
#pragma unroll
            for (int i = 0; i < 8; i++) { s += sred[i][tid]; s2 += s2red[i][tid]; }
            float* P = (p & 1) ? psB : psA;
            P[(size_t)b * 1024 + strip * 128 + tid] = s;
            P[(size_t)b * 1024 + strip * 128 + 64 + tid] = s2;
        }
    }

    // final z writeback for the head
#pragma unroll
    for (int mt = 0; mt < 4; ++mt) *(f32x4*)(z + zbase + mt * 16) = zr[mt];
}

// ================= head: GN + ReLU + GAP from NHWC z =================
__global__ __launch_bounds__(256) void headgap_kernel(const float* __restrict__ z,
    const float* __restrict__ w, const float* __restrict__ b, float* __restrict__ pooled) {
    __shared__ float r1[4][64], r2[4][64];
    __shared__ float scs[64], shs[64];
    int bq = blockIdx.x, tid = threadIdx.x;
    int c = tid & 63, g = tid >> 6;
    float s = 0.f, s2 = 0.f;
    for (int p = g; p < 1024; p += 4) {
        float v = z[((size_t)((bq << 10) + p)) * 64 + c];
        s += v; s2 += v * v;
    }
    r1[g][c] = s; r2[g][c] = s2;
    __syncthreads();
    if (tid < 64) {
        float ts = r1[0][tid] + r1[1][tid] + r1[2][tid] + r1[3][tid];
        float ts2 = r2[0][tid] + r2[1][tid] + r2[2][tid] + r2[3][tid];
        float mean = ts / 1024.f;
        float var = fmaxf(ts2 / 1024.f - mean * mean, 0.f);
        float sc = rsqrtf(var + 1e-5f) * w[tid];
        scs[tid] = sc;
        shs[tid] = b[tid] - mean * sc;
    }
    __syncthreads();
    float sc = scs[c], sh = shs[c];
    float r = 0.f;
    for (int p = g; p < 1024; p += 4)
        r += fmaxf(fmaf(z[((size_t)((bq << 10) + p)) * 64 + c], sc, sh), 0.f);
    r1[g][c] = r;
    __syncthreads();
    if (tid < 64)
        pooled[bq * 64 + tid] = (r1[0][tid] + r1[1][tid] + r1[2][tid] + r1[3][tid]) / 1024.f;
}

__global__ __launch_bounds__(256) void headfc_kernel(const float* __restrict__ pooled,
    const float* __restrict__ W, const float* __restrict__ bias, float* __restrict__ out) {
    int i = blockIdx.x * 256 + threadIdx.x;
    if (i < 640) {
        int b = i / 10, j = i % 10;
        float a = bias[j];
        const float* p = pooled + b * 64;
        const float* wj = W + j * 64;
#pragma unroll 8
        for (int c = 0; c < 64; c++) a += p[c] * wj[c];
        out[i] = a;
    }
}

extern "C" void kernel_launch(void* const* d_in, const int* in_sizes, int n_in,
                              void* d_out, int out_size, void* d_ws, size_t ws_size,
                              hipStream_t stream) {
    const float* x      = (const float*)d_in[0];
    const float* ds_w1  = (const float*)d_in[1];
    const float* ds_b1  = (const float*)d_in[2];
    const float* ds_n1w = (const float*)d_in[3];
    const float* ds_n1b = (const float*)d_in[4];
    const float* ds_w2  = (const float*)d_in[5];
    const float* ds_b2  = (const float*)d_in[6];
    const float* ds_n2w = (const float*)d_in[7];
    const float* ds_n2b = (const float*)d_in[8];
    const float* ds_w3  = (const float*)d_in[9];
    const float* ds_b3  = (const float*)d_in[10];
    const float* ode_w1 = (const float*)d_in[11];
    const float* ode_b1 = (const float*)d_in[12];
    const float* ode_n1w= (const float*)d_in[13];
    const float* ode_n1b= (const float*)d_in[14];
    const float* ode_w2 = (const float*)d_in[15];
    const float* ode_b2 = (const float*)d_in[16];
    const float* ode_n2w= (const float*)d_in[17];
    const float* ode_n2b= (const float*)d_in[18];
    const float* head_nw= (const float*)d_in[19];
    const float* head_nb= (const float*)d_in[20];
    const float* head_W = (const float*)d_in[21];
    const float* head_b = (const float*)d_in[22];

    const size_t NZ = (size_t)BB * CC * 32 * 32;   // 4,194,304
    float* ws = (float*)d_ws;
    float*          z     = ws;                                   // NZ fp32 NHWC
    unsigned short* zb    = (unsigned short*)(ws + NZ);           // NZ bf16
    unsigned short* u     = (unsigned short*)(ws + 3 * NZ / 2);   // NZ bf16
    unsigned short* v     = (unsigned short*)(ws + 2 * NZ);       // NZ bf16
    unsigned short* h2    = (unsigned short*)(ws + 5 * NZ / 2);   // 4*NZ bf16 = 2*NZ fl
    float*          apf   = ws + 9 * NZ / 2;
    unsigned short* Apk   = (unsigned short*)apf;                 // 204,800 shorts
    float*          Stab  = apf + 102400;                         // 1,152
    float*          sums  = Stab + 1152;                          // 2 slots * 8192
    float*          psA   = sums + 16384;                         // 65,536
    float*          psB   = psA + 65536;                          // 65,536
    float*          ps    = psB + 65536;                          // 32,768
    float*          ps2   = ps + 32768;                           // 32,768
    float*          gn1sc = ps2 + 32768;                          // 4,096
    float*          gn1sh = gn1sc + 4096;                         // 4,096
    float*          pooled= gn1sh + 4096;                         // 4,096

    hipMemsetAsync(sums, 0, 2 * 8192 * sizeof(float), stream);
    prepack_kernel<<<dim3(32, 4), 256, 0, stream>>>(ode_w1, ode_w2, ds_w2, ds_w3, Apk, Stab);

    // ---- downsampler (all conv on MFMA; h1 recomputed in-register) ----
    conv1stats_kernel<<<dim3(8, BB), 256, 0, stream>>>(x, ds_w1, ds_b1, ps, ps2);
    gn1fin_kernel<<<16, 256, 0, stream>>>(ps, ps2, ds_n1w, ds_n1b, gn1sc, gn1sh);
    ds2mfma_kernel<<<dim3(64, BB), 256, 0, stream>>>(x, ds_w1, ds_b1, gn1sc, gn1sh,
        Apk + 73728, ds_b2, h2, sums + 8192);
    ds3mfma_kernel<<<dim3(16, BB), 256, 0, stream>>>(h2, sums + 8192, ds_n2w, ds_n2b,
        Apk + 139264, ds_b3, z, zb, sums);

    // ---- ODE: one persistent cooperative kernel (80 convs, z/kacc in registers) ----
    {
        float* a_z = z; unsigned short* a_zb = zb; unsigned short* a_u = u;
        unsigned short* a_v = v;
        const float* a_sums0 = sums;
        float* a_psA = psA; float* a_psB = psB;
        const unsigned short* a_AP1 = Apk;
        const unsigned short* a_AP2 = Apk + 36864;
        const float* a_Stab = Stab;
        const float* a_b1 = ode_b1; const float* a_b2 = ode_b2;
        const float* a_n1w = ode_n1w; const float* a_n1b = ode_n1b;
        const float* a_n2w = ode_n2w; const float* a_n2b = ode_n2b;
        void* args[] = { &a_z, &a_zb, &a_u, &a_v, &a_sums0, &a_psA, &a_psB,
                         &a_AP1, &a_AP2, &a_Stab, &a_b1, &a_b2,
                         &a_n1w, &a_n1b, &a_n2w, &a_n2b };
        hipLaunchCooperativeKernel((void*)ode_coop_kernel, dim3(8, BB), dim3(512),
                                   args, 0, stream);
    }

    // ---- head ----
    headgap_kernel<<<BB, 256, 0, stream>>>(z, head_nw, head_nb, pooled);
    headfc_kernel<<<3, 256, 0, stream>>>(pooled, head_W, head_b, (float*)d_out);
}

// Round 6
// 5576.465 us; speedup vs baseline: 1.2006x; 1.2006x over previous
//
#include <hip/hip_runtime.h>

#define BB 64   // batch
#define CC 64   // channels

typedef __attribute__((ext_vector_type(8))) short short8;
typedef __attribute__((ext_vector_type(4))) short short4v;
typedef __attribute__((ext_vector_type(4))) float f32x4;

__device__ __forceinline__ float bf2f(unsigned short h) {
    unsigned int u = ((unsigned int)h) << 16;
    float f; __builtin_memcpy(&f, &u, 4); return f;
}
__device__ __forceinline__ unsigned short f2bf(float f) {
    unsigned int u; __builtin_memcpy(&u, &f, 4);
    u += 0x7fffu + ((u >> 16) & 1u);
    return (unsigned short)(u >> 16);
}

// ================= GN1 stats directly from x (recompute conv1) =================
__global__ __launch_bounds__(256) void conv1stats_kernel(const float* __restrict__ x,
    const float* __restrict__ w1, const float* __restrict__ b1,
    float* __restrict__ ps, float* __restrict__ ps2) {
    __shared__ float sw1[576];
    __shared__ float sb1[64];
    __shared__ float xs[10 * 130];
    int tid = threadIdx.x;
    int qq = blockIdx.x;
    int b = blockIdx.y;
    for (int i = tid; i < 576; i += 256) sw1[i] = w1[i];
    if (tid < 64) sb1[tid] = b1[tid];
    const float* xb = x + (size_t)b * 130 * 130;
    int c = tid >> 2, q = tid & 3;
    float s = 0.f, s2 = 0.f;
    for (int sidx = 0; sidx < 2; sidx++) {
        int row0 = (qq * 2 + sidx) * 8;
        __syncthreads();
        for (int i = tid; i < 1300; i += 256) xs[i] = xb[row0 * 130 + i];
        __syncthreads();
        const float* wc = &sw1[c * 9];
        float bc = sb1[c];
        for (int p = q; p < 1024; p += 4) {
            int y = p >> 7, xx = p & 127;
            float v = bc;
#pragma unroll
            for (int ky = 0; ky < 3; ky++)
#pragma unroll
                for (int kx = 0; kx < 3; kx++)
                    v += xs[(y + ky) * 130 + xx + kx] * wc[ky * 3 + kx];
            s += v; s2 += v * v;
        }
    }
    s  += __shfl_xor(s, 1, 64);  s  += __shfl_xor(s, 2, 64);
    s2 += __shfl_xor(s2, 1, 64); s2 += __shfl_xor(s2, 2, 64);
    if (q == 0) {
        ps [(b * 8 + qq) * 64 + c] = s;
        ps2[(b * 8 + qq) * 64 + c] = s2;
    }
}

__global__ __launch_bounds__(256) void gn1fin_kernel(const float* __restrict__ ps,
    const float* __restrict__ ps2, const float* __restrict__ n1w, const float* __restrict__ n1b,
    float* __restrict__ gn1sc, float* __restrict__ gn1sh) {
    int i = blockIdx.x * 256 + threadIdx.x;
    if (i >= BB * CC) return;
    int c = i & 63, b = i >> 6;
    float s = 0.f, s2 = 0.f;
#pragma unroll
    for (int qq = 0; qq < 8; qq++) {
        s  += ps [(b * 8 + qq) * 64 + c];
        s2 += ps2[(b * 8 + qq) * 64 + c];
    }
    float mean = s / 16384.f;
    float var = s2 / 16384.f - mean * mean;
    float rstd = rsqrtf(var + 1e-5f);
    float sc = rstd * n1w[c];
    gn1sc[i] = sc;
    gn1sh[i] = n1b[c] - mean * sc;
}

// ===== weight prepack, chunk-major A: Apk[kc][co][32] bf16 =====
__global__ __launch_bounds__(256) void prepack_kernel(const float* __restrict__ w1,
    const float* __restrict__ w2, const float* __restrict__ dw2,
    const float* __restrict__ dw3, unsigned short* __restrict__ Apk,
    float* __restrict__ Stab) {
    int set = blockIdx.y, kc = blockIdx.x, tid = threadIdx.x;
    int nchunk = (set < 2) ? 18 : 32;
    if (kc < nchunk) {
        const float* w = (set == 0) ? w1 : (set == 1) ? w2 : (set == 2) ? dw2 : dw3;
        size_t off = (set == 0) ? 0 : (set == 1) ? 36864 : (set == 2) ? 73728 : 139264;
        for (int e = tid; e < 2048; e += 256) {
            int co = e >> 5, j = e & 31;
            int k = kc * 32 + j;
            int ci = k & 63;
            int tap = k >> 6;
            float val;
            if (set < 2) val = w[(co * 65 + ci + 1) * 9 + tap];
            else         val = w[((co << 6) + ci) * 16 + tap];
            Apk[off + (size_t)kc * 2048 + e] = f2bf(val);
        }
    }
    if (set < 2 && kc == 0) {
        const float* w = set ? w2 : w1;
        for (int t = tid; t < 576; t += 256) {
            int co = t / 9, tap = t % 9;
            Stab[set * 576 + t] = w[(co * 65) * 9 + tap];
        }
    }
}

// ===== ds2mfma: x -> conv1 -> GN1 -> ReLU (in-register) -> conv4x4/s2 MFMA -> h2 =====
__global__ __launch_bounds__(256) void ds2mfma_kernel(const float* __restrict__ x,
    const float* __restrict__ w1, const float* __restrict__ b1,
    const float* __restrict__ gn1sc, const float* __restrict__ gn1sh,
    const unsigned short* __restrict__ Apk, const float* __restrict__ bias2,
    unsigned short* __restrict__ h2, float* __restrict__ sums_out) {
    __shared__ unsigned short X[2 * 198 * 64];
    __shared__ float xs[8 * 68];
    __shared__ float sw1[576];
    __shared__ float sb1[64], ssc[64], ssh[64], sb2[64];
    __shared__ float sred[4][64], s2red[4][64];
    int tid = threadIdx.x;
    int b = blockIdx.y;
    int bx = blockIdx.x;
    int xh = bx & 1, sy = bx >> 1;
    int lane = tid & 63, w = tid >> 6;
    int colL = lane & 15, quad = lane >> 4;

    for (int i = tid; i < 576; i += 256) sw1[i] = w1[i];
    if (tid < 64) {
        sb1[tid] = b1[tid];
        ssc[tid] = gn1sc[b * 64 + tid];
        ssh[tid] = gn1sh[b * 64 + tid];
        sb2[tid] = bias2[tid];
    }
    {
        const float* xb = x + (size_t)b * 130 * 130;
        for (int i = tid; i < 544; i += 256) {
            int r = i / 68, cc = i % 68;
            int xr = 4 * sy - 1 + r, xcg = 64 * xh - 1 + cc;
            xs[i] = (xr >= 0 && xr < 130 && xcg >= 0 && xcg < 130) ? xb[xr * 130 + xcg] : 0.f;
        }
    }
    __syncthreads();
    {
        int sub = tid & 7;
        float sbr[8], scr[8], shr[8];
#pragma unroll
        for (int e = 0; e < 8; e++) {
            int c = sub * 8 + e;
            sbr[e] = sb1[c]; scr[e] = ssc[c]; shr[e] = ssh[c];
        }
        for (int i = tid; i < 3168; i += 256) {
            int pidx = i >> 3;
            int ir = pidx / 66, ic = pidx - ir * 66;
            int gy = 4 * sy - 1 + ir, gxg = 64 * xh - 1 + ic;
            short8 o;
            if (gy >= 0 && gy < 128 && gxg >= 0 && gxg < 128) {
#pragma unroll
                for (int e = 0; e < 8; e++) {
                    int c = sub * 8 + e;
                    float v = sbr[e];
#pragma unroll
                    for (int ky = 0; ky < 3; ky++)
#pragma unroll
                        for (int kx = 0; kx < 3; kx++)
                            v += xs[(ir + ky) * 68 + ic + kx] * sw1[c * 9 + ky * 3 + kx];
                    o[e] = (short)f2bf(fmaxf(fmaf(v, scr[e], shr[e]), 0.f));
                }
            } else {
#pragma unroll
                for (int e = 0; e < 8; e++) o[e] = 0;
            }
            int p = ic & 1;
            int psx = ir * 33 + (ic >> 1);
            *(short8*)(X + ((p * 198 + psx) << 6) + ((sub ^ (psx & 7)) << 3)) = o;
        }
    }
    __syncthreads();

    int l = w >> 1, oxb = (w & 1) * 16;
    int oxl = oxb + colL;
    f32x4 acc[4] = {};
    for (int kc = 0; kc < 32; ++kc) {
        int tap = kc >> 1;
        int ky = tap >> 2, kx = tap & 3;
        int chgrp = (kc & 1) * 4 + quad;
        int ir = 2 * l + ky;
        int p = kx & 1;
        int psx = ir * 33 + oxl + (kx >> 1);
        short8 bb = *(const short8*)(X + ((p * 198 + psx) << 6) + ((chgrp ^ (psx & 7)) << 3));
        const unsigned short* ap = Apk + (((kc << 6) + colL) << 5) + (quad << 3);
        short8 a0 = *(const short8*)(ap);
        short8 a1 = *(const short8*)(ap + 512);
        short8 a2 = *(const short8*)(ap + 1024);
        short8 a3 = *(const short8*)(ap + 1536);
        acc[0] = __builtin_amdgcn_mfma_f32_16x16x32_bf16(a0, bb, acc[0], 0, 0, 0);
        acc[1] = __builtin_amdgcn_mfma_f32_16x16x32_bf16(a1, bb, acc[1], 0, 0, 0);
        acc[2] = __builtin_amdgcn_mfma_f32_16x16x32_bf16(a2, bb, acc[2], 0, 0, 0);
        acc[3] = __builtin_amdgcn_mfma_f32_16x16x32_bf16(a3, bb, acc[3], 0, 0, 0);
    }

    float sl[16], s2l[16];
#pragma unroll
    for (int i = 0; i < 16; i++) { sl[i] = 0.f; s2l[i] = 0.f; }
    int oy = 2 * sy + l, oxg = xh * 32 + oxl;
#pragma unroll
    for (int mt = 0; mt < 4; ++mt) {
        int co0 = mt * 16 + quad * 4;
        size_t base = ((size_t)((b * 64 + oy) * 64 + oxg)) * 64 + co0;
        short4v o;
#pragma unroll
        for (int r = 0; r < 4; ++r) {
            unsigned short hh = f2bf(acc[mt][r] + sb2[co0 + r]);
            o[r] = (short)hh;
            float f = bf2f(hh);
            sl[mt * 4 + r] += f; s2l[mt * 4 + r] += f * f;
        }
        *(short4v*)(h2 + base) = o;
    }
#pragma unroll
    for (int idx = 0; idx < 16; ++idx) {
        float s = sl[idx], s2 = s2l[idx];
        s += __shfl_xor(s, 1, 64); s += __shfl_xor(s, 2, 64);
        s += __shfl_xor(s, 4, 64); s += __shfl_xor(s, 8, 64);
        s2 += __shfl_xor(s2, 1, 64); s2 += __shfl_xor(s2, 2, 64);
        s2 += __shfl_xor(s2, 4, 64); s2 += __shfl_xor(s2, 8, 64);
        if (colL == 0) {
            int co = (idx >> 2) * 16 + quad * 4 + (idx & 3);
            sred[w][co] = s; s2red[w][co] = s2;
        }
    }
    __syncthreads();
    if (tid < 64) {
        float s = sred[0][tid] + sred[1][tid] + sred[2][tid] + sred[3][tid];
        float s2 = s2red[0][tid] + s2red[1][tid] + s2red[2][tid] + s2red[3][tid];
        atomicAdd(&sums_out[b * 64 + tid], s);
        atomicAdd(&sums_out[4096 + b * 64 + tid], s2);
    }
}

// ===== ds3mfma: h2(bf16 NHWC) -> GN2+ReLU on load -> conv4x4/s2 MFMA -> z,zb,sums =====
__global__ __launch_bounds__(256) void ds3mfma_kernel(const unsigned short* __restrict__ h2,
    const float* __restrict__ sums_in, const float* __restrict__ gw, const float* __restrict__ gb,
    const unsigned short* __restrict__ Apk, const float* __restrict__ bias3,
    float* __restrict__ z, unsigned short* __restrict__ zb, float* __restrict__ sums_out) {
    __shared__ unsigned short X[2 * 198 * 64];
    __shared__ float ssc[64], ssh[64], sb3[64];
    __shared__ float sred[4][64], s2red[4][64];
    int tid = threadIdx.x;
    int b = blockIdx.y, sy = blockIdx.x;
    int lane = tid & 63, w = tid >> 6;
    int colL = lane & 15, quad = lane >> 4;

    if (tid < 64) {
        int c = tid;
        float s = sums_in[b * 64 + c];
        float s2 = sums_in[4096 + b * 64 + c];
        float mean = s * (1.f / 4096.f);
        float var = fmaxf(s2 * (1.f / 4096.f) - mean * mean, 0.f);
        float sc = rsqrtf(var + 1e-5f) * gw[c];
        ssc[c] = sc;
        ssh[c] = gb[c] - mean * sc;
        sb3[c] = bias3[c];
    }
    __syncthreads();
    {
        int sub = tid & 7;
        float scr[8], shr[8];
#pragma unroll
        for (int e = 0; e < 8; e++) { scr[e] = ssc[sub * 8 + e]; shr[e] = ssh[sub * 8 + e]; }
        for (int i = tid; i < 3168; i += 256) {
            int pidx = i >> 3;
            int ir = pidx / 66, ic = pidx - ir * 66;
            int gy = 4 * sy - 1 + ir, gx = ic - 1;
            short8 o;
            if (gy >= 0 && gy < 64 && gx >= 0 && gx < 64) {
                short8 d = *(const short8*)(h2 + ((size_t)((b * 64 + gy) * 64 + gx)) * 64 + sub * 8);
#pragma unroll
                for (int e = 0; e < 8; e++) {
                    float f = bf2f((unsigned short)d[e]);
                    o[e] = (short)f2bf(fmaxf(fmaf(f, scr[e], shr[e]), 0.f));
                }
            } else {
#pragma unroll
                for (int e = 0; e < 8; e++) o[e] = 0;
            }
            int p = ic & 1;
            int psx = ir * 33 + (ic >> 1);
            *(short8*)(X + ((p * 198 + psx) << 6) + ((sub ^ (psx & 7)) << 3)) = o;
        }
    }
    __syncthreads();

    int l = w >> 1, oxb = (w & 1) * 16;
    int oxl = oxb + colL;
    f32x4 acc[4] = {};
    for (int kc = 0; kc < 32; ++kc) {
        int tap = kc >> 1;
        int ky = tap >> 2, kx = tap & 3;
        int chgrp = (kc & 1) * 4 + quad;
        int ir = 2 * l + ky;
        int p = kx & 1;
        int psx = ir * 33 + oxl + (kx >> 1);
        short8 bb = *(const short8*)(X + ((p * 198 + psx) << 6) + ((chgrp ^ (psx & 7)) << 3));
        const unsigned short* ap = Apk + (((kc << 6) + colL) << 5) + (quad << 3);
        short8 a0 = *(const short8*)(ap);
        short8 a1 = *(const short8*)(ap + 512);
        short8 a2 = *(const short8*)(ap + 1024);
        short8 a3 = *(const short8*)(ap + 1536);
        acc[0] = __builtin_amdgcn_mfma_f32_16x16x32_bf16(a0, bb, acc[0], 0, 0, 0);
        acc[1] = __builtin_amdgcn_mfma_f32_16x16x32_bf16(a1, bb, acc[1], 0, 0, 0);
        acc[2] = __builtin_amdgcn_mfma_f32_16x16x32_bf16(a2, bb, acc[2], 0, 0, 0);
        acc[3] = __builtin_amdgcn_mfma_f32_16x16x32_bf16(a3, bb, acc[3], 0, 0, 0);
    }

    float sl[16], s2l[16];
#pragma unroll
    for (int i = 0; i < 16; i++) { sl[i] = 0.f; s2l[i] = 0.f; }
    int py = 2 * sy + l;
#pragma unroll
    for (int mt = 0; mt < 4; ++mt) {
        int co0 = mt * 16 + quad * 4;
        size_t base = ((size_t)((b << 10) + py * 32 + oxl)) * 64 + co0;
        f32x4 zv;
        short4v o;
#pragma unroll
        for (int r = 0; r < 4; ++r) {
            float val = acc[mt][r] + sb3[co0 + r];
            zv[r] = val;
            unsigned short hh = f2bf(val);
            o[r] = (short)hh;
            float f = bf2f(hh);
            sl[mt * 4 + r] += f; s2l[mt * 4 + r] += f * f;
        }
        *(f32x4*)(z + base) = zv;
        *(short4v*)(zb + base) = o;
    }
#pragma unroll
    for (int idx = 0; idx < 16; ++idx) {
        float s = sl[idx], s2 = s2l[idx];
        s += __shfl_xor(s, 1, 64); s += __shfl_xor(s, 2, 64);
        s += __shfl_xor(s, 4, 64); s += __shfl_xor(s, 8, 64);
        s2 += __shfl_xor(s2, 1, 64); s2 += __shfl_xor(s2, 2, 64);
        s2 += __shfl_xor(s2, 4, 64); s2 += __shfl_xor(s2, 8, 64);
        if (colL == 0) {
            int co = (idx >> 2) * 16 + quad * 4 + (idx & 3);
            sred[w][co] = s; s2red[w][co] = s2;
        }
    }
    __syncthreads();
    if (tid < 64) {
        float s = sred[0][tid] + sred[1][tid] + sred[2][tid] + sred[3][tid];
        float s2 = s2red[0][tid] + s2red[1][tid] + s2red[2][tid] + s2red[3][tid];
        atomicAdd(&sums_out[b * 64 + tid], s);
        atomicAdd(&sums_out[4096 + b * 64 + tid], s2);
    }
}

// ==================== persistent per-sample ODE kernel ====================
// grid (64 samples, 4 strips of 8 rows) x 512 threads, 1 block/CU (LDS ~102 KB).
// z & kacc in registers for all 10 RK4 steps. Cross-block traffic: 4 u-ghost rows
// (relaxed agent atomics) + GN stats (atomicAdd) + a 4-block monotonic barrier.
// No L2 flush/invalidate anywhere.
__global__ __launch_bounds__(512, 2) void ode_persist_kernel(
    float* __restrict__ z, const unsigned short* __restrict__ zb,
    unsigned int* __restrict__ ug, float* __restrict__ S, int* __restrict__ bar,
    const unsigned short* __restrict__ AP1, const unsigned short* __restrict__ AP2,
    const float* __restrict__ Stab,
    const float* __restrict__ ob1, const float* __restrict__ ob2,
    const float* __restrict__ n1w, const float* __restrict__ n1b,
    const float* __restrict__ n2w, const float* __restrict__ n2b)
{
    extern __shared__ unsigned short smem[];
    unsigned short* X  = smem;            // 12 rows x 34 x 64 ch = 26112 shorts
    unsigned short* X2 = smem + 26112;    // 10 rows x 34 x 64 ch = 21760 shorts
    float* fp    = (float*)(smem + 47872);
    float* ssc   = fp;        float* ssh   = fp + 64;
    float* tS    = fp + 128;  float* trow0 = fp + 192;  float* trow2 = fp + 256;
    float* tcol0 = fp + 320;  float* tcol2 = fp + 384;
    float* tc00  = fp + 448;  float* tc02  = fp + 512;
    float* tc20  = fp + 576;  float* tc22  = fp + 640;
    float* sred  = fp + 704;             // [8][64]
    float* s2red = fp + 704 + 512;       // [8][64]

    const int tid = threadIdx.x;
    const int b = blockIdx.x, q = blockIdx.y;
    const int y0 = q * 8;
    const int lane = tid & 63, w = tid >> 6;
    const int colL = lane & 15, quad = lane >> 4;
    const int h = w & 1;
    const int px = h * 16 + colL;
    const bool bx0 = (px == 0), bx1 = (px == 31);
    const int r0 = w >> 1, r1 = 4 + (w >> 1);   // own rows of this wave's 2 units
    const int vrloA = (q == 0) ? 1 : 0;
    const int vrhiA = (q == 3) ? 8 : 9;

    // zero X and X2 (pads stay zero forever)
    {
        f32x4 zz = 0.f;
        for (int i = tid; i < 5984; i += 512) ((f32x4*)smem)[i] = zz;
    }

    // load z into registers
    f32x4 zr[2][4], kr[2][4];
#pragma unroll
    for (int j2 = 0; j2 < 2; ++j2) {
        int gy = y0 + (j2 ? r1 : r0);
        size_t base = ((size_t)((b << 10) + gy * 32 + px)) * 64 + quad * 4;
#pragma unroll
        for (int mt = 0; mt < 4; ++mt) {
            zr[j2][mt] = *(const f32x4*)(z + base + mt * 16);
            kr[j2][mt] = 0.f;
        }
    }
    __syncthreads();

    // pre-write X raw own rows (rows 2..9) from bf16(zr)
#pragma unroll
    for (int j2 = 0; j2 < 2; ++j2) {
        int r = j2 ? r1 : r0;
        int site = (r + 2) * 34 + px + 1;
#pragma unroll
        for (int mt = 0; mt < 4; ++mt) {
            int co0 = mt * 16 + quad * 4;
            short4v o;
#pragma unroll
            for (int e = 0; e < 4; ++e) o[e] = (short)f2bf(zr[j2][mt][e]);
            int g = co0 >> 3;
            *(short4v*)(X + (site << 6) + ((g ^ (site & 7)) << 3) + (co0 & 7)) = o;
        }
    }

    int bsync = 0;

    for (int j = 0; j < 40; ++j) {
        const int stage = j & 3;
        const float tt = 0.1f * (float)(j >> 2)
                       + ((stage == 0) ? 0.f : (stage == 3) ? 0.1f : 0.05f);

        // ---- gn1 barrier (skip j=0: slot 0 pre-filled by ds3, ghosts from zb) ----
        if (j > 0) {
            __syncthreads();
            if (tid == 0) {
                __hip_atomic_fetch_add(&bar[b], 1, __ATOMIC_RELEASE, __HIP_MEMORY_SCOPE_AGENT);
                int target = 4 * (++bsync);
                while (__hip_atomic_load(&bar[b], __ATOMIC_RELAXED, __HIP_MEMORY_SCOPE_AGENT) < target)
                    __builtin_amdgcn_s_sleep(2);
            } else ++bsync;
            __syncthreads();
            asm volatile("" ::: "memory");
        }
        // gn1 params + conv-A t-tables
        if (tid < 64) {
            const float* sp = S + (size_t)(2 * j) * 8192 + b * 64 + tid;
            float s  = __hip_atomic_load(sp,        __ATOMIC_RELAXED, __HIP_MEMORY_SCOPE_AGENT);
            float s2 = __hip_atomic_load(sp + 4096, __ATOMIC_RELAXED, __HIP_MEMORY_SCOPE_AGENT);
            float mean = s * (1.f / 1024.f);
            float var = fmaxf(s2 * (1.f / 1024.f) - mean * mean, 0.f);
            float sc = rsqrtf(var + 1e-5f) * n1w[tid];
            ssc[tid] = sc;
            ssh[tid] = n1b[tid] - mean * sc;
        } else if (tid < 128) {
            int co = tid - 64;
            float w0[9];
#pragma unroll
            for (int k = 0; k < 9; k++) w0[k] = Stab[co * 9 + k] * tt;
            tS[co] = ob1[co] + w0[0]+w0[1]+w0[2]+w0[3]+w0[4]+w0[5]+w0[6]+w0[7]+w0[8];
            trow0[co] = w0[0]+w0[1]+w0[2]; trow2[co] = w0[6]+w0[7]+w0[8];
            tcol0[co] = w0[0]+w0[3]+w0[6]; tcol2[co] = w0[2]+w0[5]+w0[8];
            tc00[co] = w0[0]; tc02[co] = w0[2]; tc20[co] = w0[6]; tc22[co] = w0[8];
        }
        __syncthreads();

        // ---- in-place normalize X own rows (2..9) ----
        for (int idx = tid; idx < 2048; idx += 512) {
            int gp = idx & 7, sidx = idx >> 3;
            int r = 2 + (sidx >> 5), c = 1 + (sidx & 31);
            int site = r * 34 + c;
            int g = gp ^ (site & 7);
            short8* pp = (short8*)(X + (site << 6) + (gp << 3));
            short8 d = *pp;
#pragma unroll
            for (int e = 0; e < 8; ++e) {
                float f = bf2f((unsigned short)d[e]);
                d[e] = (short)f2bf(fmaxf(fmaf(f, ssc[g * 8 + e], ssh[g * 8 + e]), 0.f));
            }
            *pp = d;
        }
        // ---- ghost import (rows 0,1,10,11) ----
        for (int it = 0; it < 2; ++it) {
            int idx = tid + it * 512;
            int g = idx & 7, sidx = idx >> 3;
            int gr = sidx >> 5, gpx = sidx & 31;
            int xrow = (gr < 2) ? gr : gr + 8;
            int gy = y0 - 2 + xrow;
            if (gy < 0 || gy > 31) continue;
            int site = xrow * 34 + gpx + 1;
            unsigned short tmp[8];
            size_t ebase = ((size_t)((b << 10) + gy * 32 + gpx)) * 64 + g * 8;
            if (j == 0) {
                short8 d = *(const short8*)(zb + ebase);
#pragma unroll
                for (int e = 0; e < 8; ++e) tmp[e] = (unsigned short)d[e];
            } else {
                size_t di = ebase >> 1;
#pragma unroll
                for (int u2 = 0; u2 < 4; ++u2) {
                    unsigned int dv = __hip_atomic_load(&ug[di + u2], __ATOMIC_RELAXED,
                                                        __HIP_MEMORY_SCOPE_AGENT);
                    tmp[2 * u2] = (unsigned short)(dv & 0xffffu);
                    tmp[2 * u2 + 1] = (unsigned short)(dv >> 16);
                }
            }
            short8 o;
#pragma unroll
            for (int e = 0; e < 8; ++e)
                o[e] = (short)f2bf(fmaxf(fmaf(bf2f(tmp[e]), ssc[g * 8 + e], ssh[g * 8 + e]), 0.f));
            *(short8*)(X + (site << 6) + ((g ^ (site & 7)) << 3)) = o;
        }
        __syncthreads();

        // ---- conv A: v rows y0-1..y0+8 (vr 0..9), redundant ghost depth 1 ----
        int avr[3], avalid = 0;
        f32x4 accA[3][4];
#pragma unroll
        for (int ai = 0; ai < 3; ++ai) {
            int a = w + 8 * ai;
            int vr = a >> 1;
            bool ok = (a < 20) && ((a & 1) == h) && (vr >= vrloA) && (vr <= vrhiA);
            // note: unit parity must match wave half; units are a = vr*2+h with h fixed per wave
            avr[ai] = vr;
            if (ok) avalid |= (1 << ai);
#pragma unroll
            for (int mt = 0; mt < 4; ++mt) accA[ai][mt] = 0.f;
        }
        for (int kc = 0; kc < 18; ++kc) {
            int tap = kc >> 1;
            int dy = tap / 3, dx = tap % 3;
            int chgrp = (kc & 1) * 4 + quad;
            const unsigned short* ap = AP1 + (((kc << 6) + colL) << 5) + (quad << 3);
            short8 a0 = *(const short8*)(ap);
            short8 a1 = *(const short8*)(ap + 512);
            short8 a2 = *(const short8*)(ap + 1024);
            short8 a3 = *(const short8*)(ap + 1536);
#pragma unroll
            for (int ai = 0; ai < 3; ++ai) {
                if (!(avalid & (1 << ai))) continue;
                int site = (avr[ai] + dy) * 34 + px + dx;
                short8 bb = *(const short8*)(X + (site << 6) + ((chgrp ^ (site & 7)) << 3));
                accA[ai][0] = __builtin_amdgcn_mfma_f32_16x16x32_bf16(a0, bb, accA[ai][0], 0, 0, 0);
                accA[ai][1] = __builtin_amdgcn_mfma_f32_16x16x32_bf16(a1, bb, accA[ai][1], 0, 0, 0);
                accA[ai][2] = __builtin_amdgcn_mfma_f32_16x16x32_bf16(a2, bb, accA[ai][2], 0, 0, 0);
                accA[ai][3] = __builtin_amdgcn_mfma_f32_16x16x32_bf16(a3, bb, accA[ai][3], 0, 0, 0);
            }
        }
        // epilogue A: t-correction, raw bf16 v -> X2, gn2 partials (own rows only)
        float sl[16], s2l[16];
#pragma unroll
        for (int i = 0; i < 16; i++) { sl[i] = 0.f; s2l[i] = 0.f; }
#pragma unroll
        for (int ai = 0; ai < 3; ++ai) {
            if (!(avalid & (1 << ai))) continue;
            int vr = avr[ai];
            int gy = y0 - 1 + vr;
            bool by0_ = (gy == 0), by1_ = (gy == 31);
            bool own = (vr >= 1) && (vr <= 8);
            int site = vr * 34 + px + 1;
#pragma unroll
            for (int mt = 0; mt < 4; ++mt) {
                int co0 = mt * 16 + quad * 4;
                short4v o;
#pragma unroll
                for (int e = 0; e < 4; ++e) {
                    int co = co0 + e;
                    float val = accA[ai][mt][e] + tS[co];
                    if (by0_) { val -= trow0[co]; if (bx0) val += tc00[co]; if (bx1) val += tc02[co]; }
                    if (by1_) { val -= trow2[co]; if (bx0) val += tc20[co]; if (bx1) val += tc22[co]; }
                    if (bx0) val -= tcol0[co];
                    if (bx1) val -= tcol2[co];
                    unsigned short hh = f2bf(val);
                    o[e] = (short)hh;
                    if (own) { float f = bf2f(hh); sl[mt * 4 + e] += f; s2l[mt * 4 + e] += f * f; }
                }
                int g = co0 >> 3;
                *(short4v*)(X2 + (site << 6) + ((g ^ (site & 7)) << 3) + (co0 & 7)) = o;
            }
        }
#pragma unroll
        for (int idx = 0; idx < 16; ++idx) {
            float s = sl[idx], s2 = s2l[idx];
            s += __shfl_xor(s, 1, 64); s += __shfl_xor(s, 2, 64);
            s += __shfl_xor(s, 4, 64); s += __shfl_xor(s, 8, 64);
            s2 += __shfl_xor(s2, 1, 64); s2 += __shfl_xor(s2, 2, 64);
            s2 += __shfl_xor(s2, 4, 64); s2 += __shfl_xor(s2, 8, 64);
            if (colL == 0) {
                int co = (idx >> 2) * 16 + quad * 4 + (idx & 3);
                sred[w * 64 + co] = s; s2red[w * 64 + co] = s2;
            }
        }
        __syncthreads();
        if (tid < 64) {
            float s = 0.f, s2 = 0.f;
#pragma unroll
            for (int i = 0; i < 8; i++) { s += sred[i * 64 + tid]; s2 += s2red[i * 64 + tid]; }
            float* sp = S + (size_t)(2 * j + 1) * 8192 + b * 64 + tid;
            atomicAdd(sp, s);
            atomicAdd(sp + 4096, s2);
        }

        // ---- gn2 barrier ----
        __syncthreads();
        if (tid == 0) {
            __hip_atomic_fetch_add(&bar[b], 1, __ATOMIC_RELEASE, __HIP_MEMORY_SCOPE_AGENT);
            int target = 4 * (++bsync);
            while (__hip_atomic_load(&bar[b], __ATOMIC_RELAXED, __HIP_MEMORY_SCOPE_AGENT) < target)
                __builtin_amdgcn_s_sleep(2);
        } else ++bsync;
        __syncthreads();
        asm volatile("" ::: "memory");

        // gn2 params + conv-B t-tables
        if (tid < 64) {
            const float* sp = S + (size_t)(2 * j + 1) * 8192 + b * 64 + tid;
            float s  = __hip_atomic_load(sp,        __ATOMIC_RELAXED, __HIP_MEMORY_SCOPE_AGENT);
            float s2 = __hip_atomic_load(sp + 4096, __ATOMIC_RELAXED, __HIP_MEMORY_SCOPE_AGENT);
            float mean = s * (1.f / 1024.f);
            float var = fmaxf(s2 * (1.f / 1024.f) - mean * mean, 0.f);
            float sc = rsqrtf(var + 1e-5f) * n2w[tid];
            ssc[tid] = sc;
            ssh[tid] = n2b[tid] - mean * sc;
        } else if (tid < 128) {
            int co = tid - 64;
            float w0[9];
#pragma unroll
            for (int k = 0; k < 9; k++) w0[k] = Stab[576 + co * 9 + k] * tt;
            tS[co] = ob2[co] + w0[0]+w0[1]+w0[2]+w0[3]+w0[4]+w0[5]+w0[6]+w0[7]+w0[8];
            trow0[co] = w0[0]+w0[1]+w0[2]; trow2[co] = w0[6]+w0[7]+w0[8];
            tcol0[co] = w0[0]+w0[3]+w0[6]; tcol2[co] = w0[2]+w0[5]+w0[8];
            tc00[co] = w0[0]; tc02[co] = w0[2]; tc20[co] = w0[6]; tc22[co] = w0[8];
        }
        __syncthreads();

        // ---- in-place normalize X2 valid rows ----
        {
            int nrows = vrhiA - vrloA + 1;
            int cnt = nrows * 256;
            for (int idx = tid; idx < cnt; idx += 512) {
                int gp = idx & 7, sidx = idx >> 3;
                int r = vrloA + (sidx >> 5), c = 1 + (sidx & 31);
                int site = r * 34 + c;
                int g = gp ^ (site & 7);
                short8* pp = (short8*)(X2 + (site << 6) + (gp << 3));
                short8 d = *pp;
#pragma unroll
                for (int e = 0; e < 8; ++e) {
                    float f = bf2f((unsigned short)d[e]);
                    d[e] = (short)f2bf(fmaxf(fmaf(f, ssc[g * 8 + e], ssh[g * 8 + e]), 0.f));
                }
                *pp = d;
            }
        }
        __syncthreads();

        // ---- conv B: k on own 8 rows ----
        f32x4 accB[2][4] = {};
        for (int kc = 0; kc < 18; ++kc) {
            int tap = kc >> 1;
            int dy = tap / 3, dx = tap % 3;
            int chgrp = (kc & 1) * 4 + quad;
            const unsigned short* ap = AP2 + (((kc << 6) + colL) << 5) + (quad << 3);
            short8 a0 = *(const short8*)(ap);
            short8 a1 = *(const short8*)(ap + 512);
            short8 a2 = *(const short8*)(ap + 1024);
            short8 a3 = *(const short8*)(ap + 1536);
#pragma unroll
            for (int j2 = 0; j2 < 2; ++j2) {
                int r = j2 ? r1 : r0;
                int site = (r + dy) * 34 + px + dx;
                short8 bb = *(const short8*)(X2 + (site << 6) + ((chgrp ^ (site & 7)) << 3));
                accB[j2][0] = __builtin_amdgcn_mfma_f32_16x16x32_bf16(a0, bb, accB[j2][0], 0, 0, 0);
                accB[j2][1] = __builtin_amdgcn_mfma_f32_16x16x32_bf16(a1, bb, accB[j2][1], 0, 0, 0);
                accB[j2][2] = __builtin_amdgcn_mfma_f32_16x16x32_bf16(a2, bb, accB[j2][2], 0, 0, 0);
                accB[j2][3] = __builtin_amdgcn_mfma_f32_16x16x32_bf16(a3, bb, accB[j2][3], 0, 0, 0);
            }
        }

        // ---- epilogue B: RK4 register update + next-phase y (raw X, ghost, stats) ----
        const bool last = (j == 39);
        const float anext = (stage <= 1) ? 0.05f : 0.1f;
#pragma unroll
        for (int i = 0; i < 16; i++) { sl[i] = 0.f; s2l[i] = 0.f; }
#pragma unroll
        for (int j2 = 0; j2 < 2; ++j2) {
            int r = j2 ? r1 : r0;
            int gy = y0 + r;
            bool by0_ = (gy == 0), by1_ = (gy == 31);
            int siteX = (r + 2) * 34 + px + 1;
            bool ghost = (r == 0) || (r == 1) || (r == 6) || (r == 7);
#pragma unroll
            for (int mt = 0; mt < 4; ++mt) {
                int co0 = mt * 16 + quad * 4;
                short4v o;
#pragma unroll
                for (int e = 0; e < 4; ++e) {
                    int co = co0 + e;
                    float val = accB[j2][mt][e] + tS[co];
                    if (by0_) { val -= trow0[co]; if (bx0) val += tc00[co]; if (bx1) val += tc02[co]; }
                    if (by1_) { val -= trow2[co]; if (bx0) val += tc20[co]; if (bx1) val += tc22[co]; }
                    if (bx0) val -= tcol0[co];
                    if (bx1) val -= tcol2[co];
                    float y;
                    if (stage == 0) { kr[j2][mt][e] = val; y = zr[j2][mt][e] + anext * val; }
                    else if (stage == 3) {
                        float zn = zr[j2][mt][e] + (0.1f / 6.0f) * (kr[j2][mt][e] + val);
                        zr[j2][mt][e] = zn;
                        y = zn;
                    } else { kr[j2][mt][e] += 2.f * val; y = zr[j2][mt][e] + anext * val; }
                    unsigned short hh = f2bf(y);
                    o[e] = (short)hh;
                    float f = bf2f(hh);
                    sl[mt * 4 + e] += f; s2l[mt * 4 + e] += f * f;
                }
                if (!last) {
                    int g = co0 >> 3;
                    *(short4v*)(X + (siteX << 6) + ((g ^ (siteX & 7)) << 3) + (co0 & 7)) = o;
                    if (ghost) {
                        unsigned int d0 = (unsigned int)(unsigned short)o[0]
                                        | ((unsigned int)(unsigned short)o[1] << 16);
                        unsigned int d1 = (unsigned int)(unsigned short)o[2]
                                        | ((unsigned int)(unsigned short)o[3] << 16);
                        size_t di = (((size_t)((b << 10) + gy * 32 + px)) * 64 + co0) >> 1;
                        __hip_atomic_store(&ug[di], d0, __ATOMIC_RELAXED, __HIP_MEMORY_SCOPE_AGENT);
                        __hip_atomic_store(&ug[di + 1], d1, __ATOMIC_RELAXED, __HIP_MEMORY_SCOPE_AGENT);
                    }
                }
            }
        }
        if (!last) {
#pragma unroll
            for (int idx = 0; idx < 16; ++idx) {
                float s = sl[idx], s2 = s2l[idx];
                s += __shfl_xor(s, 1, 64); s += __shfl_xor(s, 2, 64);
                s += __shfl_xor(s, 4, 64); s += __shfl_xor(s, 8, 64);
                s2 += __shfl_xor(s2, 1, 64); s2 += __shfl_xor(s2, 2, 64);
                s2 += __shfl_xor(s2, 4, 64); s2 += __shfl_xor(s2, 8, 64);
                if (colL == 0) {
                    int co = (idx >> 2) * 16 + quad * 4 + (idx & 3);
                    sred[w * 64 + co] = s; s2red[w * 64 + co] = s2;
                }
            }
            __syncthreads();
            if (tid < 64) {
                float s = 0.f, s2 = 0.f;
#pragma unroll
                for (int i = 0; i < 8; i++) { s += sred[i * 64 + tid]; s2 += s2red[i * 64 + tid]; }
                float* sp = S + (size_t)(2 * j + 2) * 8192 + b * 64 + tid;
                atomicAdd(sp, s);
                atomicAdd(sp + 4096, s2);
            }
        }
    }

    // final z writeback for the head
#pragma unroll
    for (int j2 = 0; j2 < 2; ++j2) {
        int gy = y0 + (j2 ? r1 : r0);
        size_t base = ((size_t)((b << 10) + gy * 32 + px)) * 64 + quad * 4;
#pragma unroll
        for (int mt = 0; mt < 4; ++mt) *(f32x4*)(z + base + mt * 16) = zr[j2][mt];
    }
}

// ================= head: GN + ReLU + GAP from NHWC z =================
__global__ __launch_bounds__(256) void headgap_kernel(const float* __restrict__ z,
    const float* __restrict__ w, const float* __restrict__ b, float* __restrict__ pooled) {
    __shared__ float r1[4][64], r2[4][64];
    __shared__ float scs[64], shs[64];
    int bq = blockIdx.x, tid = threadIdx.x;
    int c = tid & 63, g = tid >> 6;
    float s = 0.f, s2 = 0.f;
    for (int p = g; p < 1024; p += 4) {
        float v = z[((size_t)((bq << 10) + p)) * 64 + c];
        s += v; s2 += v * v;
    }
    r1[g][c] = s; r2[g][c] = s2;
    __syncthreads();
    if (tid < 64) {
        float ts = r1[0][tid] + r1[1][tid] + r1[2][tid] + r1[3][tid];
        float ts2 = r2[0][tid] + r2[1][tid] + r2[2][tid] + r2[3][tid];
        float mean = ts / 1024.f;
        float var = fmaxf(ts2 / 1024.f - mean * mean, 0.f);
        float sc = rsqrtf(var + 1e-5f) * w[tid];
        scs[tid] = sc;
        shs[tid] = b[tid] - mean * sc;
    }
    __syncthreads();
    float sc = scs[c], sh = shs[c];
    float r = 0.f;
    for (int p = g; p < 1024; p += 4)
        r += fmaxf(fmaf(z[((size_t)((bq << 10) + p)) * 64 + c], sc, sh), 0.f);
    r1[g][c] = r;
    __syncthreads();
    if (tid < 64)
        pooled[bq * 64 + tid] = (r1[0][tid] + r1[1][tid] + r1[2][tid] + r1[3][tid]) / 1024.f;
}

__global__ __launch_bounds__(256) void headfc_kernel(const float* __restrict__ pooled,
    const float* __restrict__ W, const float* __restrict__ bias, float* __restrict__ out) {
    int i = blockIdx.x * 256 + threadIdx.x;
    if (i < 640) {
        int b = i / 10, j = i % 10;
        float a = bias[j];
        const float* p = pooled + b * 64;
        const float* wj = W + j * 64;
#pragma unroll 8
        for (int c = 0; c < 64; c++) a += p[c] * wj[c];
        out[i] = a;
    }
}

extern "C" void kernel_launch(void* const* d_in, const int* in_sizes, int n_in,
                              void* d_out, int out_size, void* d_ws, size_t ws_size,
                              hipStream_t stream) {
    const float* x      = (const float*)d_in[0];
    const float* ds_w1  = (const float*)d_in[1];
    const float* ds_b1  = (const float*)d_in[2];
    const float* ds_n1w = (const float*)d_in[3];
    const float* ds_n1b = (const float*)d_in[4];
    const float* ds_w2  = (const float*)d_in[5];
    const float* ds_b2  = (const float*)d_in[6];
    const float* ds_n2w = (const float*)d_in[7];
    const float* ds_n2b = (const float*)d_in[8];
    const float* ds_w3  = (const float*)d_in[9];
    const float* ds_b3  = (const float*)d_in[10];
    const float* ode_w1 = (const float*)d_in[11];
    const float* ode_b1 = (const float*)d_in[12];
    const float* ode_n1w= (const float*)d_in[13];
    const float* ode_n1b= (const float*)d_in[14];
    const float* ode_w2 = (const float*)d_in[15];
    const float* ode_b2 = (const float*)d_in[16];
    const float* ode_n2w= (const float*)d_in[17];
    const float* ode_n2b= (const float*)d_in[18];
    const float* head_nw= (const float*)d_in[19];
    const float* head_nb= (const float*)d_in[20];
    const float* head_W = (const float*)d_in[21];
    const float* head_b = (const float*)d_in[22];

    const size_t NZ = (size_t)BB * CC * 32 * 32;   // 4,194,304
    float* ws = (float*)d_ws;
    float*          z     = ws;                                   // NZ fp32 NHWC
    unsigned short* zb    = (unsigned short*)(ws + NZ);           // NZ bf16
    unsigned int*   ug    = (unsigned int*)(ws + 3 * NZ / 2);     // NZ bf16 ghost buffer
    unsigned short* h2    = (unsigned short*)(ws + 2 * NZ);       // 2*NZ fl (bf16 NHWC)
    float*          apf   = ws + 4 * NZ;
    unsigned short* Apk   = (unsigned short*)apf;                 // 204,800 shorts
    float*          Stab  = apf + 102400;                         // 1,152
    float*          S     = Stab + 1152;                          // 80 slots * 8192
    int*            bar   = (int*)(S + 80 * 8192);                // 64 ints
    float*          sums2 = S + 80 * 8192 + 64;                   // ds2 GN slot (8192)
    float*          ps    = sums2 + 8192;
    float*          ps2   = ps + 32768;
    float*          gn1sc = ps2 + 32768;
    float*          gn1sh = gn1sc + 4096;
    float*          pooled= gn1sh + 4096;

    hipMemsetAsync(S, 0, (80 * 8192 + 64 + 8192) * sizeof(float), stream);
    prepack_kernel<<<dim3(32, 4), 256, 0, stream>>>(ode_w1, ode_w2, ds_w2, ds_w3, Apk, Stab);

    // ---- downsampler ----
    conv1stats_kernel<<<dim3(8, BB), 256, 0, stream>>>(x, ds_w1, ds_b1, ps, ps2);
    gn1fin_kernel<<<16, 256, 0, stream>>>(ps, ps2, ds_n1w, ds_n1b, gn1sc, gn1sh);
    ds2mfma_kernel<<<dim3(64, BB), 256, 0, stream>>>(x, ds_w1, ds_b1, gn1sc, gn1sh,
        Apk + 73728, ds_b2, h2, sums2);
    ds3mfma_kernel<<<dim3(16, BB), 256, 0, stream>>>(h2, sums2, ds_n2w, ds_n2b,
        Apk + 139264, ds_b3, z, zb, S /* slot 0 */);

    // ---- ODE: one persistent kernel, per-sample 4-block barriers ----
    {
        static int attr_set = 0;
        hipFuncSetAttribute(reinterpret_cast<const void*>(ode_persist_kernel),
                            hipFuncAttributeMaxDynamicSharedMemorySize, 102656);
        (void)attr_set;
        float* a_z = z; const unsigned short* a_zb = zb; unsigned int* a_ug = ug;
        float* a_S = S; int* a_bar = bar;
        const unsigned short* a_AP1 = Apk;
        const unsigned short* a_AP2 = Apk + 36864;
        const float* a_Stab = Stab;
        const float* a_b1 = ode_b1; const float* a_b2 = ode_b2;
        const float* a_n1w = ode_n1w; const float* a_n1b = ode_n1b;
        const float* a_n2w = ode_n2w; const float* a_n2b = ode_n2b;
        void* args[] = { &a_z, &a_zb, &a_ug, &a_S, &a_bar, &a_AP1, &a_AP2, &a_Stab,
                         &a_b1, &a_b2, &a_n1w, &a_n1b, &a_n2w, &a_n2b };
        hipLaunchCooperativeKernel((void*)ode_persist_kernel, dim3(BB, 4), dim3(512),
                                   args, 102656, stream);
    }

    // ---- head ----
    headgap_kernel<<<BB, 256, 0, stream>>>(z, head_nw, head_nb, pooled);
    headfc_kernel<<<3, 256, 0, stream>>>(pooled, head_W, head_b, (float*)d_out);
}

// Round 7
// 2597.361 us; speedup vs baseline: 2.5776x; 2.1470x over previous
//
#include <hip/hip_runtime.h>

#define BB 64   // batch
#define CC 64   // channels

typedef __attribute__((ext_vector_type(8))) short short8;
typedef __attribute__((ext_vector_type(4))) short short4v;
typedef __attribute__((ext_vector_type(4))) float f32x4;

__device__ __forceinline__ float bf2f(unsigned short h) {
    unsigned int u = ((unsigned int)h) << 16;
    float f; __builtin_memcpy(&f, &u, 4); return f;
}
__device__ __forceinline__ unsigned short f2bf(float f) {
    unsigned int u; __builtin_memcpy(&u, &f, 4);
    u += 0x7fffu + ((u >> 16) & 1u);
    return (unsigned short)(u >> 16);
}

// ================= GN1 stats directly from x (recompute conv1) =================
__global__ __launch_bounds__(256) void conv1stats_kernel(const float* __restrict__ x,
    const float* __restrict__ w1, const float* __restrict__ b1,
    float* __restrict__ ps, float* __restrict__ ps2) {
    __shared__ float sw1[576];
    __shared__ float sb1[64];
    __shared__ float xs[10 * 130];
    int tid = threadIdx.x;
    int qq = blockIdx.x;
    int b = blockIdx.y;
    for (int i = tid; i < 576; i += 256) sw1[i] = w1[i];
    if (tid < 64) sb1[tid] = b1[tid];
    const float* xb = x + (size_t)b * 130 * 130;
    int c = tid >> 2, q = tid & 3;
    float s = 0.f, s2 = 0.f;
    for (int sidx = 0; sidx < 2; sidx++) {
        int row0 = (qq * 2 + sidx) * 8;
        __syncthreads();
        for (int i = tid; i < 1300; i += 256) xs[i] = xb[row0 * 130 + i];
        __syncthreads();
        const float* wc = &sw1[c * 9];
        float bc = sb1[c];
        for (int p = q; p < 1024; p += 4) {
            int y = p >> 7, xx = p & 127;
            float v = bc;
#pragma unroll
            for (int ky = 0; ky < 3; ky++)
#pragma unroll
                for (int kx = 0; kx < 3; kx++)
                    v += xs[(y + ky) * 130 + xx + kx] * wc[ky * 3 + kx];
            s += v; s2 += v * v;
        }
    }
    s  += __shfl_xor(s, 1, 64);  s  += __shfl_xor(s, 2, 64);
    s2 += __shfl_xor(s2, 1, 64); s2 += __shfl_xor(s2, 2, 64);
    if (q == 0) {
        ps [(b * 8 + qq) * 64 + c] = s;
        ps2[(b * 8 + qq) * 64 + c] = s2;
    }
}

__global__ __launch_bounds__(256) void gn1fin_kernel(const float* __restrict__ ps,
    const float* __restrict__ ps2, const float* __restrict__ n1w, const float* __restrict__ n1b,
    float* __restrict__ gn1sc, float* __restrict__ gn1sh) {
    int i = blockIdx.x * 256 + threadIdx.x;
    if (i >= BB * CC) return;
    int c = i & 63, b = i >> 6;
    float s = 0.f, s2 = 0.f;
#pragma unroll
    for (int qq = 0; qq < 8; qq++) {
        s  += ps [(b * 8 + qq) * 64 + c];
        s2 += ps2[(b * 8 + qq) * 64 + c];
    }
    float mean = s / 16384.f;
    float var = s2 / 16384.f - mean * mean;
    float rstd = rsqrtf(var + 1e-5f);
    float sc = rstd * n1w[c];
    gn1sc[i] = sc;
    gn1sh[i] = n1b[c] - mean * sc;
}

// ===== weight prepack, chunk-major A: Apk[kc][co][32] bf16 =====
// sets: 0=ode_w1 (18 chunks), 1=ode_w2 (18), 2=ds_w2 (32), 3=ds_w3 (32)
__global__ __launch_bounds__(256) void prepack_kernel(const float* __restrict__ w1,
    const float* __restrict__ w2, const float* __restrict__ dw2,
    const float* __restrict__ dw3, unsigned short* __restrict__ Apk,
    float* __restrict__ Stab) {
    int set = blockIdx.y, kc = blockIdx.x, tid = threadIdx.x;
    int nchunk = (set < 2) ? 18 : 32;
    if (kc < nchunk) {
        const float* w = (set == 0) ? w1 : (set == 1) ? w2 : (set == 2) ? dw2 : dw3;
        size_t off = (set == 0) ? 0 : (set == 1) ? 36864 : (set == 2) ? 73728 : 139264;
        for (int e = tid; e < 2048; e += 256) {
            int co = e >> 5, j = e & 31;
            int k = kc * 32 + j;
            int ci = k & 63;
            int tap = k >> 6;
            float val;
            if (set < 2) val = w[(co * 65 + ci + 1) * 9 + tap];
            else         val = w[((co << 6) + ci) * 16 + tap];
            Apk[off + (size_t)kc * 2048 + e] = f2bf(val);
        }
    }
    if (set < 2 && kc == 0) {
        const float* w = set ? w2 : w1;
        for (int t = tid; t < 576; t += 256) {
            int co = t / 9, tap = t % 9;
            Stab[set * 576 + t] = w[(co * 65) * 9 + tap];
        }
    }
}

// ===== ds2mfma: x -> conv1 -> GN1 -> ReLU (in-register) -> conv4x4/s2 MFMA -> h2 =====
__global__ __launch_bounds__(256) void ds2mfma_kernel(const float* __restrict__ x,
    const float* __restrict__ w1, const float* __restrict__ b1,
    const float* __restrict__ gn1sc, const float* __restrict__ gn1sh,
    const unsigned short* __restrict__ Apk, const float* __restrict__ bias2,
    unsigned short* __restrict__ h2, float* __restrict__ sums_out) {
    __shared__ unsigned short X[2 * 198 * 64];
    __shared__ float xs[8 * 68];
    __shared__ float sw1[576];
    __shared__ float sb1[64], ssc[64], ssh[64], sb2[64];
    __shared__ float sred[4][64], s2red[4][64];
    int tid = threadIdx.x;
    int b = blockIdx.y;
    int bx = blockIdx.x;
    int xh = bx & 1, sy = bx >> 1;
    int lane = tid & 63, w = tid >> 6;
    int colL = lane & 15, quad = lane >> 4;

    for (int i = tid; i < 576; i += 256) sw1[i] = w1[i];
    if (tid < 64) {
        sb1[tid] = b1[tid];
        ssc[tid] = gn1sc[b * 64 + tid];
        ssh[tid] = gn1sh[b * 64 + tid];
        sb2[tid] = bias2[tid];
    }
    {
        const float* xb = x + (size_t)b * 130 * 130;
        for (int i = tid; i < 544; i += 256) {
            int r = i / 68, cc = i % 68;
            int xr = 4 * sy - 1 + r, xcg = 64 * xh - 1 + cc;
            xs[i] = (xr >= 0 && xr < 130 && xcg >= 0 && xcg < 130) ? xb[xr * 130 + xcg] : 0.f;
        }
    }
    __syncthreads();
    {
        int sub = tid & 7;
        float sbr[8], scr[8], shr[8];
#pragma unroll
        for (int e = 0; e < 8; e++) {
            int c = sub * 8 + e;
            sbr[e] = sb1[c]; scr[e] = ssc[c]; shr[e] = ssh[c];
        }
        for (int i = tid; i < 3168; i += 256) {
            int pidx = i >> 3;
            int ir = pidx / 66, ic = pidx - ir * 66;
            int gy = 4 * sy - 1 + ir, gxg = 64 * xh - 1 + ic;
            short8 o;
            if (gy >= 0 && gy < 128 && gxg >= 0 && gxg < 128) {
#pragma unroll
                for (int e = 0; e < 8; e++) {
                    int c = sub * 8 + e;
                    float v = sbr[e];
#pragma unroll
                    for (int ky = 0; ky < 3; ky++)
#pragma unroll
                        for (int kx = 0; kx < 3; kx++)
                            v += xs[(ir + ky) * 68 + ic + kx] * sw1[c * 9 + ky * 3 + kx];
                    o[e] = (short)f2bf(fmaxf(fmaf(v, scr[e], shr[e]), 0.f));
                }
            } else {
#pragma unroll
                for (int e = 0; e < 8; e++) o[e] = 0;
            }
            int p = ic & 1;
            int psx = ir * 33 + (ic >> 1);
            *(short8*)(X + ((p * 198 + psx) << 6) + ((sub ^ (psx & 7)) << 3)) = o;
        }
    }
    __syncthreads();

    int l = w >> 1, oxb = (w & 1) * 16;
    int oxl = oxb + colL;
    f32x4 acc[4] = {};
    for (int kc = 0; kc < 32; ++kc) {
        int tap = kc >> 1;
        int ky = tap >> 2, kx = tap & 3;
        int chgrp = (kc & 1) * 4 + quad;
        int ir = 2 * l + ky;
        int p = kx & 1;
        int psx = ir * 33 + oxl + (kx >> 1);
        short8 bb = *(const short8*)(X + ((p * 198 + psx) << 6) + ((chgrp ^ (psx & 7)) << 3));
        const unsigned short* ap = Apk + (((kc << 6) + colL) << 5) + (quad << 3);
        short8 a0 = *(const short8*)(ap);
        short8 a1 = *(const short8*)(ap + 512);
        short8 a2 = *(const short8*)(ap + 1024);
        short8 a3 = *(const short8*)(ap + 1536);
        acc[0] = __builtin_amdgcn_mfma_f32_16x16x32_bf16(a0, bb, acc[0], 0, 0, 0);
        acc[1] = __builtin_amdgcn_mfma_f32_16x16x32_bf16(a1, bb, acc[1], 0, 0, 0);
        acc[2] = __builtin_amdgcn_mfma_f32_16x16x32_bf16(a2, bb, acc[2], 0, 0, 0);
        acc[3] = __builtin_amdgcn_mfma_f32_16x16x32_bf16(a3, bb, acc[3], 0, 0, 0);
    }

    float sl[16], s2l[16];
#pragma unroll
    for (int i = 0; i < 16; i++) { sl[i] = 0.f; s2l[i] = 0.f; }
    int oy = 2 * sy + l, oxg = xh * 32 + oxl;
#pragma unroll
    for (int mt = 0; mt < 4; ++mt) {
        int co0 = mt * 16 + quad * 4;
        size_t base = ((size_t)((b * 64 + oy) * 64 + oxg)) * 64 + co0;
        short4v o;
#pragma unroll
        for (int r = 0; r < 4; ++r) {
            unsigned short hh = f2bf(acc[mt][r] + sb2[co0 + r]);
            o[r] = (short)hh;
            float f = bf2f(hh);
            sl[mt * 4 + r] += f; s2l[mt * 4 + r] += f * f;
        }
        *(short4v*)(h2 + base) = o;
    }
#pragma unroll
    for (int idx = 0; idx < 16; ++idx) {
        float s = sl[idx], s2 = s2l[idx];
        s += __shfl_xor(s, 1, 64); s += __shfl_xor(s, 2, 64);
        s += __shfl_xor(s, 4, 64); s += __shfl_xor(s, 8, 64);
        s2 += __shfl_xor(s2, 1, 64); s2 += __shfl_xor(s2, 2, 64);
        s2 += __shfl_xor(s2, 4, 64); s2 += __shfl_xor(s2, 8, 64);
        if (colL == 0) {
            int co = (idx >> 2) * 16 + quad * 4 + (idx & 3);
            sred[w][co] = s; s2red[w][co] = s2;
        }
    }
    __syncthreads();
    if (tid < 64) {
        float s = sred[0][tid] + sred[1][tid] + sred[2][tid] + sred[3][tid];
        float s2 = s2red[0][tid] + s2red[1][tid] + s2red[2][tid] + s2red[3][tid];
        atomicAdd(&sums_out[b * 64 + tid], s);
        atomicAdd(&sums_out[4096 + b * 64 + tid], s2);
    }
}

// ===== ds3mfma: h2(bf16 NHWC) -> GN2+ReLU on load -> conv4x4/s2 MFMA -> z,zb,sums =====
__global__ __launch_bounds__(256) void ds3mfma_kernel(const unsigned short* __restrict__ h2,
    const float* __restrict__ sums_in, const float* __restrict__ gw, const float* __restrict__ gb,
    const unsigned short* __restrict__ Apk, const float* __restrict__ bias3,
    float* __restrict__ z, unsigned short* __restrict__ zb, float* __restrict__ sums_out) {
    __shared__ unsigned short X[2 * 198 * 64];
    __shared__ float ssc[64], ssh[64], sb3[64];
    __shared__ float sred[4][64], s2red[4][64];
    int tid = threadIdx.x;
    int b = blockIdx.y, sy = blockIdx.x;
    int lane = tid & 63, w = tid >> 6;
    int colL = lane & 15, quad = lane >> 4;

    if (tid < 64) {
        int c = tid;
        float s = sums_in[b * 64 + c];
        float s2 = sums_in[4096 + b * 64 + c];
        float mean = s * (1.f / 4096.f);
        float var = fmaxf(s2 * (1.f / 4096.f) - mean * mean, 0.f);
        float sc = rsqrtf(var + 1e-5f) * gw[c];
        ssc[c] = sc;
        ssh[c] = gb[c] - mean * sc;
        sb3[c] = bias3[c];
    }
    __syncthreads();
    {
        int sub = tid & 7;
        float scr[8], shr[8];
#pragma unroll
        for (int e = 0; e < 8; e++) { scr[e] = ssc[sub * 8 + e]; shr[e] = ssh[sub * 8 + e]; }
        for (int i = tid; i < 3168; i += 256) {
            int pidx = i >> 3;
            int ir = pidx / 66, ic = pidx - ir * 66;
            int gy = 4 * sy - 1 + ir, gx = ic - 1;
            short8 o;
            if (gy >= 0 && gy < 64 && gx >= 0 && gx < 64) {
                short8 d = *(const short8*)(h2 + ((size_t)((b * 64 + gy) * 64 + gx)) * 64 + sub * 8);
#pragma unroll
                for (int e = 0; e < 8; e++) {
                    float f = bf2f((unsigned short)d[e]);
                    o[e] = (short)f2bf(fmaxf(fmaf(f, scr[e], shr[e]), 0.f));
                }
            } else {
#pragma unroll
                for (int e = 0; e < 8; e++) o[e] = 0;
            }
            int p = ic & 1;
            int psx = ir * 33 + (ic >> 1);
            *(short8*)(X + ((p * 198 + psx) << 6) + ((sub ^ (psx & 7)) << 3)) = o;
        }
    }
    __syncthreads();

    int l = w >> 1, oxb = (w & 1) * 16;
    int oxl = oxb + colL;
    f32x4 acc[4] = {};
    for (int kc = 0; kc < 32; ++kc) {
        int tap = kc >> 1;
        int ky = tap >> 2, kx = tap & 3;
        int chgrp = (kc & 1) * 4 + quad;
        int ir = 2 * l + ky;
        int p = kx & 1;
        int psx = ir * 33 + oxl + (kx >> 1);
        short8 bb = *(const short8*)(X + ((p * 198 + psx) << 6) + ((chgrp ^ (psx & 7)) << 3));
        const unsigned short* ap = Apk + (((kc << 6) + colL) << 5) + (quad << 3);
        short8 a0 = *(const short8*)(ap);
        short8 a1 = *(const short8*)(ap + 512);
        short8 a2 = *(const short8*)(ap + 1024);
        short8 a3 = *(const short8*)(ap + 1536);
        acc[0] = __builtin_amdgcn_mfma_f32_16x16x32_bf16(a0, bb, acc[0], 0, 0, 0);
        acc[1] = __builtin_amdgcn_mfma_f32_16x16x32_bf16(a1, bb, acc[1], 0, 0, 0);
        acc[2] = __builtin_amdgcn_mfma_f32_16x16x32_bf16(a2, bb, acc[2], 0, 0, 0);
        acc[3] = __builtin_amdgcn_mfma_f32_16x16x32_bf16(a3, bb, acc[3], 0, 0, 0);
    }

    float sl[16], s2l[16];
#pragma unroll
    for (int i = 0; i < 16; i++) { sl[i] = 0.f; s2l[i] = 0.f; }
    int py = 2 * sy + l;
#pragma unroll
    for (int mt = 0; mt < 4; ++mt) {
        int co0 = mt * 16 + quad * 4;
        size_t base = ((size_t)((b << 10) + py * 32 + oxl)) * 64 + co0;
        f32x4 zv;
        short4v o;
#pragma unroll
        for (int r = 0; r < 4; ++r) {
            float val = acc[mt][r] + sb3[co0 + r];
            zv[r] = val;
            unsigned short hh = f2bf(val);
            o[r] = (short)hh;
            float f = bf2f(hh);
            sl[mt * 4 + r] += f; s2l[mt * 4 + r] += f * f;
        }
        *(f32x4*)(z + base) = zv;
        *(short4v*)(zb + base) = o;
    }
#pragma unroll
    for (int idx = 0; idx < 16; ++idx) {
        float s = sl[idx], s2 = s2l[idx];
        s += __shfl_xor(s, 1, 64); s += __shfl_xor(s, 2, 64);
        s += __shfl_xor(s, 4, 64); s += __shfl_xor(s, 8, 64);
        s2 += __shfl_xor(s2, 1, 64); s2 += __shfl_xor(s2, 2, 64);
        s2 += __shfl_xor(s2, 4, 64); s2 += __shfl_xor(s2, 8, 64);
        if (colL == 0) {
            int co = (idx >> 2) * 16 + quad * 4 + (idx & 3);
            sred[w][co] = s; s2red[w][co] = s2;
        }
    }
    __syncthreads();
    if (tid < 64) {
        float s = sred[0][tid] + sred[1][tid] + sred[2][tid] + sred[3][tid];
        float s2 = s2red[0][tid] + s2red[1][tid] + s2red[2][tid] + s2red[3][tid];
        atomicAdd(&sums_out[b * 64 + tid], s);
        atomicAdd(&sums_out[4096 + b * 64 + tid], s2);
    }
}

// ==================== MFMA implicit-GEMM ODE conv (3x3 pad1, 64+t -> 64) ============
// strip = 4 rows; grid (8, B); block 256 = 4 waves, each wave: M=64 x N=32 (one row).
// modes: 3: uout=bf16(val)+stats; 0: kacc=val, uout=bf16(z+aa*val)+stats;
// 1: kacc+=2*val, uout=bf16(z+aa*val)+stats; 2: z+=aa*(kacc+val), uout(zb)=bf16(z)+stats.
__global__ __launch_bounds__(256) void convmfma_kernel(
    const unsigned short* __restrict__ uin, const float* __restrict__ sums_in,
    const float* __restrict__ gw, const float* __restrict__ gb,
    const unsigned short* __restrict__ Apk, const float* __restrict__ stab,
    const float* __restrict__ bias, float t, float aa, int mode,
    float* __restrict__ z, unsigned short* __restrict__ uout,
    float* __restrict__ kacc, float* __restrict__ sums_out)
{
    __shared__ unsigned short X[6 * 34 * 64];    // 13056 shorts, swizzled
    __shared__ float ssc[64], ssh[64];
    __shared__ float tS[64], trow0[64], trow2[64], tcol0[64], tcol2[64];
    __shared__ float tc00[64], tc02[64], tc20[64], tc22[64];
    __shared__ float sred[4][64], s2red[4][64];

    int tid = threadIdx.x;
    int b = blockIdx.y, strip = blockIdx.x;
    int y0 = strip * 4;
    int lane = tid & 63, w = tid >> 6;
    int colL = lane & 15, quad = lane >> 4;

    {   // zero X (pad cols / OOB rows stay zero)
        f32x4 zz = 0.f;
        for (int i = tid; i < 1632; i += 256) ((f32x4*)X)[i] = zz;
    }
    if (tid < 64) {
        int c = tid;
        float s = sums_in[b * 64 + c];
        float s2 = sums_in[4096 + b * 64 + c];
        float mean = s * (1.f / 1024.f);
        float var = fmaxf(s2 * (1.f / 1024.f) - mean * mean, 0.f);
        float sc = rsqrtf(var + 1e-5f) * gw[c];
        ssc[c] = sc;
        ssh[c] = gb[c] - mean * sc;
    } else if (tid < 128) {
        int co = tid - 64;
        float w0[9];
#pragma unroll
        for (int k = 0; k < 9; k++) w0[k] = stab[co * 9 + k] * t;
        tS[co] = bias[co] + w0[0]+w0[1]+w0[2]+w0[3]+w0[4]+w0[5]+w0[6]+w0[7]+w0[8];
        trow0[co] = w0[0] + w0[1] + w0[2];
        trow2[co] = w0[6] + w0[7] + w0[8];
        tcol0[co] = w0[0] + w0[3] + w0[6];
        tcol2[co] = w0[2] + w0[5] + w0[8];
        tc00[co] = w0[0]; tc02[co] = w0[2]; tc20[co] = w0[6]; tc22[co] = w0[8];
    }
    __syncthreads();

    {   // stage 6 input rows (GN+ReLU on load): 6 x 32 px x 8 ch-groups = 1536 short8
        int sub = tid & 7;
        float scr[8], shr[8];
#pragma unroll
        for (int e = 0; e < 8; e++) { scr[e] = ssc[sub * 8 + e]; shr[e] = ssh[sub * 8 + e]; }
#pragma unroll
        for (int it = 0; it < 6; ++it) {
            int i = tid + it * 256;
            int pidx = i >> 3;
            int xc = pidx & 31, r = pidx >> 5;
            int gy = y0 - 1 + r;
            if (gy < 0 || gy > 31) continue;
            int gp = (b << 10) + gy * 32 + xc;
            short8 d = *(const short8*)(uin + (size_t)gp * 64 + sub * 8);
            short8 o;
#pragma unroll
            for (int e = 0; e < 8; e++) {
                float f = bf2f((unsigned short)d[e]);
                o[e] = (short)f2bf(fmaxf(fmaf(f, scr[e], shr[e]), 0.f));
            }
            int psx = r * 34 + xc + 1;
            *(short8*)(X + (psx << 6) + ((sub ^ (psx & 7)) << 3)) = o;
        }
    }
    __syncthreads();

    // K-loop: wave w computes output row py = y0 + w, all 64 co, 32 px (2 n-tiles)
    f32x4 acc[4][2] = {};
    for (int kc = 0; kc < 18; ++kc) {
        int tap = kc >> 1;
        int dy = tap / 3, dx = tap % 3;
        int chgrp = (kc & 1) * 4 + quad;
        int ps0 = (w + dy) * 34 + colL + dx;
        int ps1 = ps0 + 16;
        short8 bb0 = *(const short8*)(X + (ps0 << 6) + ((chgrp ^ (ps0 & 7)) << 3));
        short8 bb1 = *(const short8*)(X + (ps1 << 6) + ((chgrp ^ (ps1 & 7)) << 3));
        const unsigned short* ap = Apk + (((kc << 6) + colL) << 5) + (quad << 3);
        short8 a0 = *(const short8*)(ap);
        short8 a1 = *(const short8*)(ap + 512);
        short8 a2 = *(const short8*)(ap + 1024);
        short8 a3 = *(const short8*)(ap + 1536);
        acc[0][0] = __builtin_amdgcn_mfma_f32_16x16x32_bf16(a0, bb0, acc[0][0], 0, 0, 0);
        acc[0][1] = __builtin_amdgcn_mfma_f32_16x16x32_bf16(a0, bb1, acc[0][1], 0, 0, 0);
        acc[1][0] = __builtin_amdgcn_mfma_f32_16x16x32_bf16(a1, bb0, acc[1][0], 0, 0, 0);
        acc[1][1] = __builtin_amdgcn_mfma_f32_16x16x32_bf16(a1, bb1, acc[1][1], 0, 0, 0);
        acc[2][0] = __builtin_amdgcn_mfma_f32_16x16x32_bf16(a2, bb0, acc[2][0], 0, 0, 0);
        acc[2][1] = __builtin_amdgcn_mfma_f32_16x16x32_bf16(a2, bb1, acc[2][1], 0, 0, 0);
        acc[3][0] = __builtin_amdgcn_mfma_f32_16x16x32_bf16(a3, bb0, acc[3][0], 0, 0, 0);
        acc[3][1] = __builtin_amdgcn_mfma_f32_16x16x32_bf16(a3, bb1, acc[3][1], 0, 0, 0);
    }

    // epilogue
    float sl[16], s2l[16];
#pragma unroll
    for (int i = 0; i < 16; i++) { sl[i] = 0.f; s2l[i] = 0.f; }
    int py = y0 + w;
    bool by0 = (py == 0), by1 = (py == 31);
#pragma unroll
    for (int nt = 0; nt < 2; ++nt) {
        int px = nt * 16 + colL;
        bool bx0 = (px == 0), bx1 = (px == 31);
#pragma unroll
        for (int mt = 0; mt < 4; ++mt) {
            int co0 = mt * 16 + quad * 4;
            float vout[4];
#pragma unroll
            for (int r = 0; r < 4; ++r) {
                int co = co0 + r;
                float val = acc[mt][nt][r] + tS[co];
                if (by0) { val -= trow0[co]; if (bx0) val += tc00[co]; if (bx1) val += tc02[co]; }
                if (by1) { val -= trow2[co]; if (bx0) val += tc20[co]; if (bx1) val += tc22[co]; }
                if (bx0) val -= tcol0[co];
                if (bx1) val -= tcol2[co];
                vout[r] = val;
            }
            size_t base = ((size_t)((b << 10) + py * 32 + px)) * 64 + co0;
            if (mode == 3) {
                short4v o;
#pragma unroll
                for (int r = 0; r < 4; ++r) {
                    unsigned short hh = f2bf(vout[r]);
                    o[r] = (short)hh;
                    float f = bf2f(hh);
                    sl[mt * 4 + r] += f; s2l[mt * 4 + r] += f * f;
                }
                *(short4v*)(uout + base) = o;
            } else if (mode == 2) {
                f32x4 kv = *(const f32x4*)(kacc + base);
                f32x4 zv = *(const f32x4*)(z + base);
                short4v o;
#pragma unroll
                for (int r = 0; r < 4; ++r) {
                    float zn = zv[r] + aa * (kv[r] + vout[r]);
                    zv[r] = zn;
                    unsigned short hh = f2bf(zn);
                    o[r] = (short)hh;
                    float f = bf2f(hh);
                    sl[mt * 4 + r] += f; s2l[mt * 4 + r] += f * f;
                }
                *(f32x4*)(z + base) = zv;
                *(short4v*)(uout + base) = o;
            } else {
                f32x4 zv = *(const f32x4*)(z + base);
                f32x4 kv;
                if (mode == 1) {
                    kv = *(const f32x4*)(kacc + base);
#pragma unroll
                    for (int r = 0; r < 4; ++r) kv[r] += 2.f * vout[r];
                } else {
#pragma unroll
                    for (int r = 0; r < 4; ++r) kv[r] = vout[r];
                }
                *(f32x4*)(kacc + base) = kv;
                short4v o;
#pragma unroll
                for (int r = 0; r < 4; ++r) {
                    unsigned short hh = f2bf(zv[r] + aa * vout[r]);
                    o[r] = (short)hh;
                    float f = bf2f(hh);
                    sl[mt * 4 + r] += f; s2l[mt * 4 + r] += f * f;
                }
                *(short4v*)(uout + base) = o;
            }
        }
    }
#pragma unroll
    for (int idx = 0; idx < 16; ++idx) {
        float s = sl[idx], s2 = s2l[idx];
        s += __shfl_xor(s, 1, 64); s += __shfl_xor(s, 2, 64);
        s += __shfl_xor(s, 4, 64); s += __shfl_xor(s, 8, 64);
        s2 += __shfl_xor(s2, 1, 64); s2 += __shfl_xor(s2, 2, 64);
        s2 += __shfl_xor(s2, 4, 64); s2 += __shfl_xor(s2, 8, 64);
        if (colL == 0) {
            int co = (idx >> 2) * 16 + quad * 4 + (idx & 3);
            sred[w][co] = s; s2red[w][co] = s2;
        }
    }
    __syncthreads();
    if (tid < 64) {
        float s = sred[0][tid] + sred[1][tid] + sred[2][tid] + sred[3][tid];
        float s2 = s2red[0][tid] + s2red[1][tid] + s2red[2][tid] + s2red[3][tid];
        atomicAdd(&sums_out[b * 64 + tid], s);
        atomicAdd(&sums_out[4096 + b * 64 + tid], s2);
    }
}

// ================= head: GN + ReLU + GAP from NHWC z =================
__global__ __launch_bounds__(256) void headgap_kernel(const float* __restrict__ z,
    const float* __restrict__ w, const float* __restrict__ b, float* __restrict__ pooled) {
    __shared__ float r1[4][64], r2[4][64];
    __shared__ float scs[64], shs[64];
    int bq = blockIdx.x, tid = threadIdx.x;
    int c = tid & 63, g = tid >> 6;
    float s = 0.f, s2 = 0.f;
    for (int p = g; p < 1024; p += 4) {
        float v = z[((size_t)((bq << 10) + p)) * 64 + c];
        s += v; s2 += v * v;
    }
    r1[g][c] = s; r2[g][c] = s2;
    __syncthreads();
    if (tid < 64) {
        float ts = r1[0][tid] + r1[1][tid] + r1[2][tid] + r1[3][tid];
        float ts2 = r2[0][tid] + r2[1][tid] + r2[2][tid] + r2[3][tid];
        float mean = ts / 1024.f;
        float var = fmaxf(ts2 / 1024.f - mean * mean, 0.f);
        float sc = rsqrtf(var + 1e-5f) * w[tid];
        scs[tid] = sc;
        shs[tid] = b[tid] - mean * sc;
    }
    __syncthreads();
    float sc = scs[c], sh = shs[c];
    float r = 0.f;
    for (int p = g; p < 1024; p += 4)
        r += fmaxf(fmaf(z[((size_t)((bq << 10) + p)) * 64 + c], sc, sh), 0.f);
    r1[g][c] = r;
    __syncthreads();
    if (tid < 64)
        pooled[bq * 64 + tid] = (r1[0][tid] + r1[1][tid] + r1[2][tid] + r1[3][tid]) / 1024.f;
}

__global__ __launch_bounds__(256) void headfc_kernel(const float* __restrict__ pooled,
    const float* __restrict__ W, const float* __restrict__ bias, float* __restrict__ out) {
    int i = blockIdx.x * 256 + threadIdx.x;
    if (i < 640) {
        int b = i / 10, j = i % 10;
        float a = bias[j];
        const float* p = pooled + b * 64;
        const float* wj = W + j * 64;
#pragma unroll 8
        for (int c = 0; c < 64; c++) a += p[c] * wj[c];
        out[i] = a;
    }
}

extern "C" void kernel_launch(void* const* d_in, const int* in_sizes, int n_in,
                              void* d_out, int out_size, void* d_ws, size_t ws_size,
                              hipStream_t stream) {
    const float* x      = (const float*)d_in[0];
    const float* ds_w1  = (const float*)d_in[1];
    const float* ds_b1  = (const float*)d_in[2];
    const float* ds_n1w = (const float*)d_in[3];
    const float* ds_n1b = (const float*)d_in[4];
    const float* ds_w2  = (const float*)d_in[5];
    const float* ds_b2  = (const float*)d_in[6];
    const float* ds_n2w = (const float*)d_in[7];
    const float* ds_n2b = (const float*)d_in[8];
    const float* ds_w3  = (const float*)d_in[9];
    const float* ds_b3  = (const float*)d_in[10];
    const float* ode_w1 = (const float*)d_in[11];
    const float* ode_b1 = (const float*)d_in[12];
    const float* ode_n1w= (const float*)d_in[13];
    const float* ode_n1b= (const float*)d_in[14];
    const float* ode_w2 = (const float*)d_in[15];
    const float* ode_b2 = (const float*)d_in[16];
    const float* ode_n2w= (const float*)d_in[17];
    const float* ode_n2b= (const float*)d_in[18];
    const float* head_nw= (const float*)d_in[19];
    const float* head_nb= (const float*)d_in[20];
    const float* head_W = (const float*)d_in[21];
    const float* head_b = (const float*)d_in[22];

    const size_t NZ = (size_t)BB * CC * 32 * 32;   // 4,194,304
    float* ws = (float*)d_ws;
    float*          z     = ws;                                   // NZ fp32 NHWC
    unsigned short* zb    = (unsigned short*)(ws + NZ);           // NZ bf16
    unsigned short* u     = (unsigned short*)(ws + 3 * NZ / 2);   // NZ bf16
    unsigned short* v     = (unsigned short*)(ws + 2 * NZ);       // NZ bf16
    float*          kacc  = ws + 5 * NZ / 2;                      // NZ fp32
    unsigned short* h2    = u;   // [B,64,64,64] NHWC bf16 = 2*NZ floats, dead by ODE
    float*          apf   = ws + 7 * NZ / 2;
    unsigned short* Apk   = (unsigned short*)apf;                 // 204,800 shorts
    float*          Stab  = apf + 102400;                         // 1,152
    float*          sums  = Stab + 1152;                          // 82 slots * 8192
    float*          ps    = sums + 82 * 8192;                     // 32,768
    float*          ps2   = ps + 32768;                           // 32,768
    float*          gn1sc = ps2 + 32768;                          // 4,096
    float*          gn1sh = gn1sc + 4096;                         // 4,096
    float*          pooled= gn1sh + 4096;                         // 4,096

    auto SUM = [&](int s) { return sums + (size_t)s * 8192; };
    auto SV = [&](int i, int j) { return 1 + i * 7 + j; };
    auto SU = [&](int i, int j) { return 1 + i * 7 + 4 + j; };
    auto ZS = [&](int i) { return 71 + i; };
    const int H2S = 81;

    hipMemsetAsync(sums, 0, 82 * 8192 * sizeof(float), stream);
    prepack_kernel<<<dim3(32, 4), 256, 0, stream>>>(ode_w1, ode_w2, ds_w2, ds_w3, Apk, Stab);

    // ---- downsampler (all conv on MFMA; h1 recomputed in-register) ----
    conv1stats_kernel<<<dim3(8, BB), 256, 0, stream>>>(x, ds_w1, ds_b1, ps, ps2);
    gn1fin_kernel<<<16, 256, 0, stream>>>(ps, ps2, ds_n1w, ds_n1b, gn1sc, gn1sh);
    ds2mfma_kernel<<<dim3(64, BB), 256, 0, stream>>>(x, ds_w1, ds_b1, gn1sc, gn1sh,
        Apk + 73728, ds_b2, h2, SUM(H2S));
    ds3mfma_kernel<<<dim3(16, BB), 256, 0, stream>>>(h2, SUM(H2S), ds_n2w, ds_n2b,
        Apk + 139264, ds_b3, z, zb, SUM(0));

    // ---- ODE: 10 RK4 steps; zupd folded into mode-2 epilogue ----
    const unsigned short* AP1 = Apk;
    const unsigned short* AP2 = Apk + 36864;
    const float* ST1 = Stab;
    const float* ST2 = Stab + 576;
    const float c6 = 0.1f / 6.0f;
    dim3 cgrid(8, BB);
    for (int i = 0; i < 10; i++) {
        float t0 = 0.1f * (float)i;
        int zslot = (i == 0) ? 0 : ZS(i - 1);
        // k1
        convmfma_kernel<<<cgrid, 256, 0, stream>>>(zb, SUM(zslot), ode_n1w, ode_n1b,
            AP1, ST1, ode_b1, t0, 0.f, 3, z, v, kacc, SUM(SV(i, 0)));
        convmfma_kernel<<<cgrid, 256, 0, stream>>>(v, SUM(SV(i, 0)), ode_n2w, ode_n2b,
            AP2, ST2, ode_b2, t0, 0.05f, 0, z, u, kacc, SUM(SU(i, 0)));
        // k2
        convmfma_kernel<<<cgrid, 256, 0, stream>>>(u, SUM(SU(i, 0)), ode_n1w, ode_n1b,
            AP1, ST1, ode_b1, t0 + 0.05f, 0.f, 3, z, v, kacc, SUM(SV(i, 1)));
        convmfma_kernel<<<cgrid, 256, 0, stream>>>(v, SUM(SV(i, 1)), ode_n2w, ode_n2b,
            AP2, ST2, ode_b2, t0 + 0.05f, 0.05f, 1, z, u, kacc, SUM(SU(i, 1)));
        // k3
        convmfma_kernel<<<cgrid, 256, 0, stream>>>(u, SUM(SU(i, 1)), ode_n1w, ode_n1b,
            AP1, ST1, ode_b1, t0 + 0.05f, 0.f, 3, z, v, kacc, SUM(SV(i, 2)));
        convmfma_kernel<<<cgrid, 256, 0, stream>>>(v, SUM(SV(i, 2)), ode_n2w, ode_n2b,
            AP2, ST2, ode_b2, t0 + 0.05f, 0.1f, 1, z, u, kacc, SUM(SU(i, 2)));
        // k4
        convmfma_kernel<<<cgrid, 256, 0, stream>>>(u, SUM(SU(i, 2)), ode_n1w, ode_n1b,
            AP1, ST1, ode_b1, t0 + 0.1f, 0.f, 3, z, v, kacc, SUM(SV(i, 3)));
        convmfma_kernel<<<cgrid, 256, 0, stream>>>(v, SUM(SV(i, 3)), ode_n2w, ode_n2b,
            AP2, ST2, ode_b2, t0 + 0.1f, c6, 2, z, zb, kacc, SUM(ZS(i)));
    }

    // ---- head ----
    headgap_kernel<<<BB, 256, 0, stream>>>(z, head_nw, head_nb, pooled);
    headfc_kernel<<<3, 256, 0, stream>>>(pooled, head_W, head_b, (float*)d_out);
}

// Round 8
// 2250.392 us; speedup vs baseline: 2.9751x; 1.1542x over previous
//
#include <hip/hip_runtime.h>

#define BB 64   // batch
#define CC 64   // channels

typedef __attribute__((ext_vector_type(8))) short short8;
typedef __attribute__((ext_vector_type(4))) short short4v;
typedef __attribute__((ext_vector_type(4))) float f32x4;

__device__ __forceinline__ float bf2f(unsigned short h) {
    unsigned int u = ((unsigned int)h) << 16;
    float f; __builtin_memcpy(&f, &u, 4); return f;
}
__device__ __forceinline__ unsigned short f2bf(float f) {
    unsigned int u; __builtin_memcpy(&u, &f, 4);
    u += 0x7fffu + ((u >> 16) & 1u);
    return (unsigned short)(u >> 16);
}

// ================= GN1 stats directly from x (recompute conv1) =================
__global__ __launch_bounds__(256) void conv1stats_kernel(const float* __restrict__ x,
    const float* __restrict__ w1, const float* __restrict__ b1,
    float* __restrict__ ps, float* __restrict__ ps2) {
    __shared__ float sw1[576];
    __shared__ float sb1[64];
    __shared__ float xs[10 * 130];
    int tid = threadIdx.x;
    int qq = blockIdx.x;
    int b = blockIdx.y;
    for (int i = tid; i < 576; i += 256) sw1[i] = w1[i];
    if (tid < 64) sb1[tid] = b1[tid];
    const float* xb = x + (size_t)b * 130 * 130;
    int c = tid >> 2, q = tid & 3;
    float s = 0.f, s2 = 0.f;
    for (int sidx = 0; sidx < 2; sidx++) {
        int row0 = (qq * 2 + sidx) * 8;
        __syncthreads();
        for (int i = tid; i < 1300; i += 256) xs[i] = xb[row0 * 130 + i];
        __syncthreads();
        const float* wc = &sw1[c * 9];
        float bc = sb1[c];
        for (int p = q; p < 1024; p += 4) {
            int y = p >> 7, xx = p & 127;
            float v = bc;
#pragma unroll
            for (int ky = 0; ky < 3; ky++)
#pragma unroll
                for (int kx = 0; kx < 3; kx++)
                    v += xs[(y + ky) * 130 + xx + kx] * wc[ky * 3 + kx];
            s += v; s2 += v * v;
        }
    }
    s  += __shfl_xor(s, 1, 64);  s  += __shfl_xor(s, 2, 64);
    s2 += __shfl_xor(s2, 1, 64); s2 += __shfl_xor(s2, 2, 64);
    if (q == 0) {
        ps [(b * 8 + qq) * 64 + c] = s;
        ps2[(b * 8 + qq) * 64 + c] = s2;
    }
}

__global__ __launch_bounds__(256) void gn1fin_kernel(const float* __restrict__ ps,
    const float* __restrict__ ps2, const float* __restrict__ n1w, const float* __restrict__ n1b,
    float* __restrict__ gn1sc, float* __restrict__ gn1sh) {
    int i = blockIdx.x * 256 + threadIdx.x;
    if (i >= BB * CC) return;
    int c = i & 63, b = i >> 6;
    float s = 0.f, s2 = 0.f;
#pragma unroll
    for (int qq = 0; qq < 8; qq++) {
        s  += ps [(b * 8 + qq) * 64 + c];
        s2 += ps2[(b * 8 + qq) * 64 + c];
    }
    float mean = s / 16384.f;
    float var = s2 / 16384.f - mean * mean;
    float rstd = rsqrtf(var + 1e-5f);
    float sc = rstd * n1w[c];
    gn1sc[i] = sc;
    gn1sh[i] = n1b[c] - mean * sc;
}

// ===== weight prepack, chunk-major A: Apk[kc][co][32] bf16 =====
// sets: 0=ode_w1 (18 chunks), 1=ode_w2 (18), 2=ds_w2 (32), 3=ds_w3 (32)
__global__ __launch_bounds__(256) void prepack_kernel(const float* __restrict__ w1,
    const float* __restrict__ w2, const float* __restrict__ dw2,
    const float* __restrict__ dw3, unsigned short* __restrict__ Apk,
    float* __restrict__ Stab) {
    int set = blockIdx.y, kc = blockIdx.x, tid = threadIdx.x;
    int nchunk = (set < 2) ? 18 : 32;
    if (kc < nchunk) {
        const float* w = (set == 0) ? w1 : (set == 1) ? w2 : (set == 2) ? dw2 : dw3;
        size_t off = (set == 0) ? 0 : (set == 1) ? 36864 : (set == 2) ? 73728 : 139264;
        for (int e = tid; e < 2048; e += 256) {
            int co = e >> 5, j = e & 31;
            int k = kc * 32 + j;
            int ci = k & 63;
            int tap = k >> 6;
            float val;
            if (set < 2) val = w[(co * 65 + ci + 1) * 9 + tap];
            else         val = w[((co << 6) + ci) * 16 + tap];
            Apk[off + (size_t)kc * 2048 + e] = f2bf(val);
        }
    }
    if (set < 2 && kc == 0) {
        const float* w = set ? w2 : w1;
        for (int t = tid; t < 576; t += 256) {
            int co = t / 9, tap = t % 9;
            Stab[set * 576 + t] = w[(co * 65) * 9 + tap];
        }
    }
}

// ===== ds2mfma: x -> conv1 -> GN1 -> ReLU (in-register) -> conv4x4/s2 MFMA -> h2 =====
__global__ __launch_bounds__(256) void ds2mfma_kernel(const float* __restrict__ x,
    const float* __restrict__ w1, const float* __restrict__ b1,
    const float* __restrict__ gn1sc, const float* __restrict__ gn1sh,
    const unsigned short* __restrict__ Apk, const float* __restrict__ bias2,
    unsigned short* __restrict__ h2, float* __restrict__ sums_out) {
    __shared__ unsigned short X[2 * 198 * 64];
    __shared__ float xs[8 * 68];
    __shared__ float sw1[576];
    __shared__ float sb1[64], ssc[64], ssh[64], sb2[64];
    __shared__ float sred[4][64], s2red[4][64];
    int tid = threadIdx.x;
    int b = blockIdx.y;
    int bx = blockIdx.x;
    int xh = bx & 1, sy = bx >> 1;
    int lane = tid & 63, w = tid >> 6;
    int colL = lane & 15, quad = lane >> 4;

    for (int i = tid; i < 576; i += 256) sw1[i] = w1[i];
    if (tid < 64) {
        sb1[tid] = b1[tid];
        ssc[tid] = gn1sc[b * 64 + tid];
        ssh[tid] = gn1sh[b * 64 + tid];
        sb2[tid] = bias2[tid];
    }
    {
        const float* xb = x + (size_t)b * 130 * 130;
        for (int i = tid; i < 544; i += 256) {
            int r = i / 68, cc = i % 68;
            int xr = 4 * sy - 1 + r, xcg = 64 * xh - 1 + cc;
            xs[i] = (xr >= 0 && xr < 130 && xcg >= 0 && xcg < 130) ? xb[xr * 130 + xcg] : 0.f;
        }
    }
    __syncthreads();
    {
        int sub = tid & 7;
        float sbr[8], scr[8], shr[8];
#pragma unroll
        for (int e = 0; e < 8; e++) {
            int c = sub * 8 + e;
            sbr[e] = sb1[c]; scr[e] = ssc[c]; shr[e] = ssh[c];
        }
        for (int i = tid; i < 3168; i += 256) {
            int pidx = i >> 3;
            int ir = pidx / 66, ic = pidx - ir * 66;
            int gy = 4 * sy - 1 + ir, gxg = 64 * xh - 1 + ic;
            short8 o;
            if (gy >= 0 && gy < 128 && gxg >= 0 && gxg < 128) {
#pragma unroll
                for (int e = 0; e < 8; e++) {
                    int c = sub * 8 + e;
                    float v = sbr[e];
#pragma unroll
                    for (int ky = 0; ky < 3; ky++)
#pragma unroll
                        for (int kx = 0; kx < 3; kx++)
                            v += xs[(ir + ky) * 68 + ic + kx] * sw1[c * 9 + ky * 3 + kx];
                    o[e] = (short)f2bf(fmaxf(fmaf(v, scr[e], shr[e]), 0.f));
                }
            } else {
#pragma unroll
                for (int e = 0; e < 8; e++) o[e] = 0;
            }
            int p = ic & 1;
            int psx = ir * 33 + (ic >> 1);
            *(short8*)(X + ((p * 198 + psx) << 6) + ((sub ^ (psx & 7)) << 3)) = o;
        }
    }
    __syncthreads();

    int l = w >> 1, oxb = (w & 1) * 16;
    int oxl = oxb + colL;
    f32x4 acc[4] = {};
    for (int kc = 0; kc < 32; ++kc) {
        int tap = kc >> 1;
        int ky = tap >> 2, kx = tap & 3;
        int chgrp = (kc & 1) * 4 + quad;
        int ir = 2 * l + ky;
        int p = kx & 1;
        int psx = ir * 33 + oxl + (kx >> 1);
        short8 bb = *(const short8*)(X + ((p * 198 + psx) << 6) + ((chgrp ^ (psx & 7)) << 3));
        const unsigned short* ap = Apk + (((kc << 6) + colL) << 5) + (quad << 3);
        short8 a0 = *(const short8*)(ap);
        short8 a1 = *(const short8*)(ap + 512);
        short8 a2 = *(const short8*)(ap + 1024);
        short8 a3 = *(const short8*)(ap + 1536);
        acc[0] = __builtin_amdgcn_mfma_f32_16x16x32_bf16(a0, bb, acc[0], 0, 0, 0);
        acc[1] = __builtin_amdgcn_mfma_f32_16x16x32_bf16(a1, bb, acc[1], 0, 0, 0);
        acc[2] = __builtin_amdgcn_mfma_f32_16x16x32_bf16(a2, bb, acc[2], 0, 0, 0);
        acc[3] = __builtin_amdgcn_mfma_f32_16x16x32_bf16(a3, bb, acc[3], 0, 0, 0);
    }

    float sl[16], s2l[16];
#pragma unroll
    for (int i = 0; i < 16; i++) { sl[i] = 0.f; s2l[i] = 0.f; }
    int oy = 2 * sy + l, oxg = xh * 32 + oxl;
#pragma unroll
    for (int mt = 0; mt < 4; ++mt) {
        int co0 = mt * 16 + quad * 4;
        size_t base = ((size_t)((b * 64 + oy) * 64 + oxg)) * 64 + co0;
        short4v o;
#pragma unroll
        for (int r = 0; r < 4; ++r) {
            unsigned short hh = f2bf(acc[mt][r] + sb2[co0 + r]);
            o[r] = (short)hh;
            float f = bf2f(hh);
            sl[mt * 4 + r] += f; s2l[mt * 4 + r] += f * f;
        }
        *(short4v*)(h2 + base) = o;
    }
#pragma unroll
    for (int idx = 0; idx < 16; ++idx) {
        float s = sl[idx], s2 = s2l[idx];
        s += __shfl_xor(s, 1, 64); s += __shfl_xor(s, 2, 64);
        s += __shfl_xor(s, 4, 64); s += __shfl_xor(s, 8, 64);
        s2 += __shfl_xor(s2, 1, 64); s2 += __shfl_xor(s2, 2, 64);
        s2 += __shfl_xor(s2, 4, 64); s2 += __shfl_xor(s2, 8, 64);
        if (colL == 0) {
            int co = (idx >> 2) * 16 + quad * 4 + (idx & 3);
            sred[w][co] = s; s2red[w][co] = s2;
        }
    }
    __syncthreads();
    if (tid < 64) {
        float s = sred[0][tid] + sred[1][tid] + sred[2][tid] + sred[3][tid];
        float s2 = s2red[0][tid] + s2red[1][tid] + s2red[2][tid] + s2red[3][tid];
        atomicAdd(&sums_out[b * 64 + tid], s);
        atomicAdd(&sums_out[4096 + b * 64 + tid], s2);
    }
}

// ===== ds3mfma: h2(bf16 NHWC) -> GN2+ReLU on load -> conv4x4/s2 MFMA -> z,zb,sums =====
__global__ __launch_bounds__(256) void ds3mfma_kernel(const unsigned short* __restrict__ h2,
    const float* __restrict__ sums_in, const float* __restrict__ gw, const float* __restrict__ gb,
    const unsigned short* __restrict__ Apk, const float* __restrict__ bias3,
    float* __restrict__ z, unsigned short* __restrict__ zb, float* __restrict__ sums_out) {
    __shared__ unsigned short X[2 * 198 * 64];
    __shared__ float ssc[64], ssh[64], sb3[64];
    __shared__ float sred[4][64], s2red[4][64];
    int tid = threadIdx.x;
    int b = blockIdx.y, sy = blockIdx.x;
    int lane = tid & 63, w = tid >> 6;
    int colL = lane & 15, quad = lane >> 4;

    if (tid < 64) {
        int c = tid;
        float s = sums_in[b * 64 + c];
        float s2 = sums_in[4096 + b * 64 + c];
        float mean = s * (1.f / 4096.f);
        float var = fmaxf(s2 * (1.f / 4096.f) - mean * mean, 0.f);
        float sc = rsqrtf(var + 1e-5f) * gw[c];
        ssc[c] = sc;
        ssh[c] = gb[c] - mean * sc;
        sb3[c] = bias3[c];
    }
    __syncthreads();
    {
        int sub = tid & 7;
        float scr[8], shr[8];
#pragma unroll
        for (int e = 0; e < 8; e++) { scr[e] = ssc[sub * 8 + e]; shr[e] = ssh[sub * 8 + e]; }
        for (int i = tid; i < 3168; i += 256) {
            int pidx = i >> 3;
            int ir = pidx / 66, ic = pidx - ir * 66;
            int gy = 4 * sy - 1 + ir, gx = ic - 1;
            short8 o;
            if (gy >= 0 && gy < 64 && gx >= 0 && gx < 64) {
                short8 d = *(const short8*)(h2 + ((size_t)((b * 64 + gy) * 64 + gx)) * 64 + sub * 8);
#pragma unroll
                for (int e = 0; e < 8; e++) {
                    float f = bf2f((unsigned short)d[e]);
                    o[e] = (short)f2bf(fmaxf(fmaf(f, scr[e], shr[e]), 0.f));
                }
            } else {
#pragma unroll
                for (int e = 0; e < 8; e++) o[e] = 0;
            }
            int p = ic & 1;
            int psx = ir * 33 + (ic >> 1);
            *(short8*)(X + ((p * 198 + psx) << 6) + ((sub ^ (psx & 7)) << 3)) = o;
        }
    }
    __syncthreads();

    int l = w >> 1, oxb = (w & 1) * 16;
    int oxl = oxb + colL;
    f32x4 acc[4] = {};
    for (int kc = 0; kc < 32; ++kc) {
        int tap = kc >> 1;
        int ky = tap >> 2, kx = tap & 3;
        int chgrp = (kc & 1) * 4 + quad;
        int ir = 2 * l + ky;
        int p = kx & 1;
        int psx = ir * 33 + oxl + (kx >> 1);
        short8 bb = *(const short8*)(X + ((p * 198 + psx) << 6) + ((chgrp ^ (psx & 7)) << 3));
        const unsigned short* ap = Apk + (((kc << 6) + colL) << 5) + (quad << 3);
        short8 a0 = *(const short8*)(ap);
        short8 a1 = *(const short8*)(ap + 512);
        short8 a2 = *(const short8*)(ap + 1024);
        short8 a3 = *(const short8*)(ap + 1536);
        acc[0] = __builtin_amdgcn_mfma_f32_16x16x32_bf16(a0, bb, acc[0], 0, 0, 0);
        acc[1] = __builtin_amdgcn_mfma_f32_16x16x32_bf16(a1, bb, acc[1], 0, 0, 0);
        acc[2] = __builtin_amdgcn_mfma_f32_16x16x32_bf16(a2, bb, acc[2], 0, 0, 0);
        acc[3] = __builtin_amdgcn_mfma_f32_16x16x32_bf16(a3, bb, acc[3], 0, 0, 0);
    }

    float sl[16], s2l[16];
#pragma unroll
    for (int i = 0; i < 16; i++) { sl[i] = 0.f; s2l[i] = 0.f; }
    int py = 2 * sy + l;
#pragma unroll
    for (int mt = 0; mt < 4; ++mt) {
        int co0 = mt * 16 + quad * 4;
        size_t base = ((size_t)((b << 10) + py * 32 + oxl)) * 64 + co0;
        f32x4 zv;
        short4v o;
#pragma unroll
        for (int r = 0; r < 4; ++r) {
            float val = acc[mt][r] + sb3[co0 + r];
            zv[r] = val;
            unsigned short hh = f2bf(val);
            o[r] = (short)hh;
            float f = bf2f(hh);
            sl[mt * 4 + r] += f; s2l[mt * 4 + r] += f * f;
        }
        *(f32x4*)(z + base) = zv;
        *(short4v*)(zb + base) = o;
    }
#pragma unroll
    for (int idx = 0; idx < 16; ++idx) {
        float s = sl[idx], s2 = s2l[idx];
        s += __shfl_xor(s, 1, 64); s += __shfl_xor(s, 2, 64);
        s += __shfl_xor(s, 4, 64); s += __shfl_xor(s, 8, 64);
        s2 += __shfl_xor(s2, 1, 64); s2 += __shfl_xor(s2, 2, 64);
        s2 += __shfl_xor(s2, 4, 64); s2 += __shfl_xor(s2, 8, 64);
        if (colL == 0) {
            int co = (idx >> 2) * 16 + quad * 4 + (idx & 3);
            sred[w][co] = s; s2red[w][co] = s2;
        }
    }
    __syncthreads();
    if (tid < 64) {
        float s = sred[0][tid] + sred[1][tid] + sred[2][tid] + sred[3][tid];
        float s2 = s2red[0][tid] + s2red[1][tid] + s2red[2][tid] + s2red[3][tid];
        atomicAdd(&sums_out[b * 64 + tid], s);
        atomicAdd(&sums_out[4096 + b * 64 + tid], s2);
    }
}

// ==================== MFMA implicit-GEMM ODE conv (3x3 pad1, 64+t -> 64) ============
// strip = 8 rows; grid (4, B); block 512 = 8 waves, each wave: M=64 x N=32 (one row).
// A-matrix (72 KB) staged in LDS ONCE per block (kills the per-wave L2 A-stream).
// LDS (dynamic): Aw 73728 B + X (10 rows) 43520 B + tables 7168 B = 124416 B -> 1 block/CU.
// modes: 3: uout=bf16(val)+stats; 0: kacc=val, uout=bf16(z+aa*val)+stats;
// 1: kacc+=2*val, uout=bf16(z+aa*val)+stats; 2: z+=aa*(kacc+val), uout(zb)=bf16(z)+stats.
#define CONV_LDS_BYTES 124416
__global__ __launch_bounds__(512, 2) void convmfma_kernel(
    const unsigned short* __restrict__ uin, const float* __restrict__ sums_in,
    const float* __restrict__ gw, const float* __restrict__ gb,
    const unsigned short* __restrict__ Apk, const float* __restrict__ stab,
    const float* __restrict__ bias, float t, float aa, int mode,
    float* __restrict__ z, unsigned short* __restrict__ uout,
    float* __restrict__ kacc, float* __restrict__ sums_out)
{
    extern __shared__ unsigned short smem[];
    unsigned short* Aw = smem;                    // 36864 shorts (73728 B)
    unsigned short* X  = smem + 36864;            // 21760 shorts (10*34*64)
    float* fp    = (float*)(smem + 36864 + 21760);
    float* ssc   = fp;        float* ssh   = fp + 64;
    float* tS    = fp + 128;  float* trow0 = fp + 192;  float* trow2 = fp + 256;
    float* tcol0 = fp + 320;  float* tcol2 = fp + 384;
    float* tc00  = fp + 448;  float* tc02  = fp + 512;
    float* tc20  = fp + 576;  float* tc22  = fp + 640;
    float* sred  = fp + 704;             // [8][64]
    float* s2red = fp + 1216;            // [8][64]

    int tid = threadIdx.x;
    int b = blockIdx.y, strip = blockIdx.x;
    int y0 = strip * 8;
    int lane = tid & 63, w = tid >> 6;   // w = 0..7 (one output row per wave)
    int colL = lane & 15, quad = lane >> 4;

    {   // zero X (pad cols / OOB rows stay zero)
        f32x4 zz = 0.f;
        for (int i = tid; i < 2720; i += 512) ((f32x4*)X)[i] = zz;
    }
    // load full A (18 chunks x 64 co x 32 k) into LDS — once per block
    for (int i = tid; i < 4608; i += 512) ((f32x4*)Aw)[i] = ((const f32x4*)Apk)[i];

    if (tid < 64) {
        int c = tid;
        float s = sums_in[b * 64 + c];
        float s2 = sums_in[4096 + b * 64 + c];
        float mean = s * (1.f / 1024.f);
        float var = fmaxf(s2 * (1.f / 1024.f) - mean * mean, 0.f);
        float sc = rsqrtf(var + 1e-5f) * gw[c];
        ssc[c] = sc;
        ssh[c] = gb[c] - mean * sc;
    } else if (tid < 128) {
        int co = tid - 64;
        float w0[9];
#pragma unroll
        for (int k = 0; k < 9; k++) w0[k] = stab[co * 9 + k] * t;
        tS[co] = bias[co] + w0[0]+w0[1]+w0[2]+w0[3]+w0[4]+w0[5]+w0[6]+w0[7]+w0[8];
        trow0[co] = w0[0] + w0[1] + w0[2];
        trow2[co] = w0[6] + w0[7] + w0[8];
        tcol0[co] = w0[0] + w0[3] + w0[6];
        tcol2[co] = w0[2] + w0[5] + w0[8];
        tc00[co] = w0[0]; tc02[co] = w0[2]; tc20[co] = w0[6]; tc22[co] = w0[8];
    }
    __syncthreads();

    {   // stage 10 input rows (GN+ReLU on load): 10 x 32 px x 8 ch-groups
        int sub = tid & 7;
        float scr[8], shr[8];
#pragma unroll
        for (int e = 0; e < 8; e++) { scr[e] = ssc[sub * 8 + e]; shr[e] = ssh[sub * 8 + e]; }
#pragma unroll
        for (int it = 0; it < 5; ++it) {
            int pidx = (tid >> 3) + it * 64;     // 0..319 = 10 rows x 32 cols
            int r = pidx >> 5, xc = pidx & 31;
            int gy = y0 - 1 + r;
            if (gy < 0 || gy > 31) continue;
            int gp = (b << 10) + gy * 32 + xc;
            short8 d = *(const short8*)(uin + (size_t)gp * 64 + sub * 8);
            short8 o;
#pragma unroll
            for (int e = 0; e < 8; e++) {
                float f = bf2f((unsigned short)d[e]);
                o[e] = (short)f2bf(fmaxf(fmaf(f, scr[e], shr[e]), 0.f));
            }
            int psx = r * 34 + xc + 1;
            *(short8*)(X + (psx << 6) + ((sub ^ (psx & 7)) << 3)) = o;
        }
    }
    __syncthreads();

    // K-loop: wave w computes output row py = y0 + w, all 64 co, 32 px (2 n-tiles)
    f32x4 acc[4][2] = {};
    for (int kc = 0; kc < 18; ++kc) {
        int tap = kc >> 1;
        int dy = tap / 3, dx = tap % 3;
        int chgrp = (kc & 1) * 4 + quad;
        int ps0 = (w + dy) * 34 + colL + dx;
        int ps1 = ps0 + 16;
        short8 bb0 = *(const short8*)(X + (ps0 << 6) + ((chgrp ^ (ps0 & 7)) << 3));
        short8 bb1 = *(const short8*)(X + (ps1 << 6) + ((chgrp ^ (ps1 & 7)) << 3));
        const unsigned short* ap = Aw + (((kc << 6) + colL) << 5) + (quad << 3);
        short8 a0 = *(const short8*)(ap);
        short8 a1 = *(const short8*)(ap + 512);
        short8 a2 = *(const short8*)(ap + 1024);
        short8 a3 = *(const short8*)(ap + 1536);
        acc[0][0] = __builtin_amdgcn_mfma_f32_16x16x32_bf16(a0, bb0, acc[0][0], 0, 0, 0);
        acc[0][1] = __builtin_amdgcn_mfma_f32_16x16x32_bf16(a0, bb1, acc[0][1], 0, 0, 0);
        acc[1][0] = __builtin_amdgcn_mfma_f32_16x16x32_bf16(a1, bb0, acc[1][0], 0, 0, 0);
        acc[1][1] = __builtin_amdgcn_mfma_f32_16x16x32_bf16(a1, bb1, acc[1][1], 0, 0, 0);
        acc[2][0] = __builtin_amdgcn_mfma_f32_16x16x32_bf16(a2, bb0, acc[2][0], 0, 0, 0);
        acc[2][1] = __builtin_amdgcn_mfma_f32_16x16x32_bf16(a2, bb1, acc[2][1], 0, 0, 0);
        acc[3][0] = __builtin_amdgcn_mfma_f32_16x16x32_bf16(a3, bb0, acc[3][0], 0, 0, 0);
        acc[3][1] = __builtin_amdgcn_mfma_f32_16x16x32_bf16(a3, bb1, acc[3][1], 0, 0, 0);
    }

    // epilogue
    float sl[16], s2l[16];
#pragma unroll
    for (int i = 0; i < 16; i++) { sl[i] = 0.f; s2l[i] = 0.f; }
    int py = y0 + w;
    bool by0 = (py == 0), by1 = (py == 31);
#pragma unroll
    for (int nt = 0; nt < 2; ++nt) {
        int px = nt * 16 + colL;
        bool bx0 = (px == 0), bx1 = (px == 31);
#pragma unroll
        for (int mt = 0; mt < 4; ++mt) {
            int co0 = mt * 16 + quad * 4;
            float vout[4];
#pragma unroll
            for (int r = 0; r < 4; ++r) {
                int co = co0 + r;
                float val = acc[mt][nt][r] + tS[co];
                if (by0) { val -= trow0[co]; if (bx0) val += tc00[co]; if (bx1) val += tc02[co]; }
                if (by1) { val -= trow2[co]; if (bx0) val += tc20[co]; if (bx1) val += tc22[co]; }
                if (bx0) val -= tcol0[co];
                if (bx1) val -= tcol2[co];
                vout[r] = val;
            }
            size_t base = ((size_t)((b << 10) + py * 32 + px)) * 64 + co0;
            if (mode == 3) {
                short4v o;
#pragma unroll
                for (int r = 0; r < 4; ++r) {
                    unsigned short hh = f2bf(vout[r]);
                    o[r] = (short)hh;
                    float f = bf2f(hh);
                    sl[mt * 4 + r] += f; s2l[mt * 4 + r] += f * f;
                }
                *(short4v*)(uout + base) = o;
            } else if (mode == 2) {
                f32x4 kv = *(const f32x4*)(kacc + base);
                f32x4 zv = *(const f32x4*)(z + base);
                short4v o;
#pragma unroll
                for (int r = 0; r < 4; ++r) {
                    float zn = zv[r] + aa * (kv[r] + vout[r]);
                    zv[r] = zn;
                    unsigned short hh = f2bf(zn);
                    o[r] = (short)hh;
                    float f = bf2f(hh);
                    sl[mt * 4 + r] += f; s2l[mt * 4 + r] += f * f;
                }
                *(f32x4*)(z + base) = zv;
                *(short4v*)(uout + base) = o;
            } else {
                f32x4 zv = *(const f32x4*)(z + base);
                f32x4 kv;
                if (mode == 1) {
                    kv = *(const f32x4*)(kacc + base);
#pragma unroll
                    for (int r = 0; r < 4; ++r) kv[r] += 2.f * vout[r];
                } else {
#pragma unroll
                    for (int r = 0; r < 4; ++r) kv[r] = vout[r];
                }
                *(f32x4*)(kacc + base) = kv;
                short4v o;
#pragma unroll
                for (int r = 0; r < 4; ++r) {
                    unsigned short hh = f2bf(zv[r] + aa * vout[r]);
                    o[r] = (short)hh;
                    float f = bf2f(hh);
                    sl[mt * 4 + r] += f; s2l[mt * 4 + r] += f * f;
                }
                *(short4v*)(uout + base) = o;
            }
        }
    }
#pragma unroll
    for (int idx = 0; idx < 16; ++idx) {
        float s = sl[idx], s2 = s2l[idx];
        s += __shfl_xor(s, 1, 64); s += __shfl_xor(s, 2, 64);
        s += __shfl_xor(s, 4, 64); s += __shfl_xor(s, 8, 64);
        s2 += __shfl_xor(s2, 1, 64); s2 += __shfl_xor(s2, 2, 64);
        s2 += __shfl_xor(s2, 4, 64); s2 += __shfl_xor(s2, 8, 64);
        if (colL == 0) {
            int co = (idx >> 2) * 16 + quad * 4 + (idx & 3);
            sred[w * 64 + co] = s; s2red[w * 64 + co] = s2;
        }
    }
    __syncthreads();
    if (tid < 64) {
        float s = 0.f, s2 = 0.f;
#pragma unroll
        for (int i = 0; i < 8; i++) { s += sred[i * 64 + tid]; s2 += s2red[i * 64 + tid]; }
        atomicAdd(&sums_out[b * 64 + tid], s);
        atomicAdd(&sums_out[4096 + b * 64 + tid], s2);
    }
}

// ================= head: GN + ReLU + GAP from NHWC z =================
__global__ __launch_bounds__(256) void headgap_kernel(const float* __restrict__ z,
    const float* __restrict__ w, const float* __restrict__ b, float* __restrict__ pooled) {
    __shared__ float r1[4][64], r2[4][64];
    __shared__ float scs[64], shs[64];
    int bq = blockIdx.x, tid = threadIdx.x;
    int c = tid & 63, g = tid >> 6;
    float s = 0.f, s2 = 0.f;
    for (int p = g; p < 1024; p += 4) {
        float v = z[((size_t)((bq << 10) + p)) * 64 + c];
        s += v; s2 += v * v;
    }
    r1[g][c] = s; r2[g][c] = s2;
    __syncthreads();
    if (tid < 64) {
        float ts = r1[0][tid] + r1[1][tid] + r1[2][tid] + r1[3][tid];
        float ts2 = r2[0][tid] + r2[1][tid] + r2[2][tid] + r2[3][tid];
        float mean = ts / 1024.f;
        float var = fmaxf(ts2 / 1024.f - mean * mean, 0.f);
        float sc = rsqrtf(var + 1e-5f) * w[tid];
        scs[tid] = sc;
        shs[tid] = b[tid] - mean * sc;
    }
    __syncthreads();
    float sc = scs[c], sh = shs[c];
    float r = 0.f;
    for (int p = g; p < 1024; p += 4)
        r += fmaxf(fmaf(z[((size_t)((bq << 10) + p)) * 64 + c], sc, sh), 0.f);
    r1[g][c] = r;
    __syncthreads();
    if (tid < 64)
        pooled[bq * 64 + tid] = (r1[0][tid] + r1[1][tid] + r1[2][tid] + r1[3][tid]) / 1024.f;
}

__global__ __launch_bounds__(256) void headfc_kernel(const float* __restrict__ pooled,
    const float* __restrict__ W, const float* __restrict__ bias, float* __restrict__ out) {
    int i = blockIdx.x * 256 + threadIdx.x;
    if (i < 640) {
        int b = i / 10, j = i % 10;
        float a = bias[j];
        const float* p = pooled + b * 64;
        const float* wj = W + j * 64;
#pragma unroll 8
        for (int c = 0; c < 64; c++) a += p[c] * wj[c];
        out[i] = a;
    }
}

extern "C" void kernel_launch(void* const* d_in, const int* in_sizes, int n_in,
                              void* d_out, int out_size, void* d_ws, size_t ws_size,
                              hipStream_t stream) {
    const float* x      = (const float*)d_in[0];
    const float* ds_w1  = (const float*)d_in[1];
    const float* ds_b1  = (const float*)d_in[2];
    const float* ds_n1w = (const float*)d_in[3];
    const float* ds_n1b = (const float*)d_in[4];
    const float* ds_w2  = (const float*)d_in[5];
    const float* ds_b2  = (const float*)d_in[6];
    const float* ds_n2w = (const float*)d_in[7];
    const float* ds_n2b = (const float*)d_in[8];
    const float* ds_w3  = (const float*)d_in[9];
    const float* ds_b3  = (const float*)d_in[10];
    const float* ode_w1 = (const float*)d_in[11];
    const float* ode_b1 = (const float*)d_in[12];
    const float* ode_n1w= (const float*)d_in[13];
    const float* ode_n1b= (const float*)d_in[14];
    const float* ode_w2 = (const float*)d_in[15];
    const float* ode_b2 = (const float*)d_in[16];
    const float* ode_n2w= (const float*)d_in[17];
    const float* ode_n2b= (const float*)d_in[18];
    const float* head_nw= (const float*)d_in[19];
    const float* head_nb= (const float*)d_in[20];
    const float* head_W = (const float*)d_in[21];
    const float* head_b = (const float*)d_in[22];

    const size_t NZ = (size_t)BB * CC * 32 * 32;   // 4,194,304
    float* ws = (float*)d_ws;
    float*          z     = ws;                                   // NZ fp32 NHWC
    unsigned short* zb    = (unsigned short*)(ws + NZ);           // NZ bf16
    unsigned short* u     = (unsigned short*)(ws + 3 * NZ / 2);   // NZ bf16
    unsigned short* v     = (unsigned short*)(ws + 2 * NZ);       // NZ bf16
    float*          kacc  = ws + 5 * NZ / 2;                      // NZ fp32
    unsigned short* h2    = u;   // [B,64,64,64] NHWC bf16 = 2*NZ floats, dead by ODE
    float*          apf   = ws + 7 * NZ / 2;
    unsigned short* Apk   = (unsigned short*)apf;                 // 204,800 shorts
    float*          Stab  = apf + 102400;                         // 1,152
    float*          sums  = Stab + 1152;                          // 82 slots * 8192
    float*          ps    = sums + 82 * 8192;                     // 32,768
    float*          ps2   = ps + 32768;                           // 32,768
    float*          gn1sc = ps2 + 32768;                          // 4,096
    float*          gn1sh = gn1sc + 4096;                         // 4,096
    float*          pooled= gn1sh + 4096;                         // 4,096

    auto SUM = [&](int s) { return sums + (size_t)s * 8192; };
    auto SV = [&](int i, int j) { return 1 + i * 7 + j; };
    auto SU = [&](int i, int j) { return 1 + i * 7 + 4 + j; };
    auto ZS = [&](int i) { return 71 + i; };
    const int H2S = 81;

    hipFuncSetAttribute(reinterpret_cast<const void*>(convmfma_kernel),
                        hipFuncAttributeMaxDynamicSharedMemorySize, CONV_LDS_BYTES);

    hipMemsetAsync(sums, 0, 82 * 8192 * sizeof(float), stream);
    prepack_kernel<<<dim3(32, 4), 256, 0, stream>>>(ode_w1, ode_w2, ds_w2, ds_w3, Apk, Stab);

    // ---- downsampler (all conv on MFMA; h1 recomputed in-register) ----
    conv1stats_kernel<<<dim3(8, BB), 256, 0, stream>>>(x, ds_w1, ds_b1, ps, ps2);
    gn1fin_kernel<<<16, 256, 0, stream>>>(ps, ps2, ds_n1w, ds_n1b, gn1sc, gn1sh);
    ds2mfma_kernel<<<dim3(64, BB), 256, 0, stream>>>(x, ds_w1, ds_b1, gn1sc, gn1sh,
        Apk + 73728, ds_b2, h2, SUM(H2S));
    ds3mfma_kernel<<<dim3(16, BB), 256, 0, stream>>>(h2, SUM(H2S), ds_n2w, ds_n2b,
        Apk + 139264, ds_b3, z, zb, SUM(0));

    // ---- ODE: 10 RK4 steps; zupd folded into mode-2 epilogue ----
    const unsigned short* AP1 = Apk;
    const unsigned short* AP2 = Apk + 36864;
    const float* ST1 = Stab;
    const float* ST2 = Stab + 576;
    const float c6 = 0.1f / 6.0f;
    dim3 cgrid(4, BB);
    for (int i = 0; i < 10; i++) {
        float t0 = 0.1f * (float)i;
        int zslot = (i == 0) ? 0 : ZS(i - 1);
        // k1
        convmfma_kernel<<<cgrid, 512, CONV_LDS_BYTES, stream>>>(zb, SUM(zslot), ode_n1w, ode_n1b,
            AP1, ST1, ode_b1, t0, 0.f, 3, z, v, kacc, SUM(SV(i, 0)));
        convmfma_kernel<<<cgrid, 512, CONV_LDS_BYTES, stream>>>(v, SUM(SV(i, 0)), ode_n2w, ode_n2b,
            AP2, ST2, ode_b2, t0, 0.05f, 0, z, u, kacc, SUM(SU(i, 0)));
        // k2
        convmfma_kernel<<<cgrid, 512, CONV_LDS_BYTES, stream>>>(u, SUM(SU(i, 0)), ode_n1w, ode_n1b,
            AP1, ST1, ode_b1, t0 + 0.05f, 0.f, 3, z, v, kacc, SUM(SV(i, 1)));
        convmfma_kernel<<<cgrid, 512, CONV_LDS_BYTES, stream>>>(v, SUM(SV(i, 1)), ode_n2w, ode_n2b,
            AP2, ST2, ode_b2, t0 + 0.05f, 0.05f, 1, z, u, kacc, SUM(SU(i, 1)));
        // k3
        convmfma_kernel<<<cgrid, 512, CONV_LDS_BYTES, stream>>>(u, SUM(SU(i, 1)), ode_n1w, ode_n1b,
            AP1, ST1, ode_b1, t0 + 0.05f, 0.f, 3, z, v, kacc, SUM(SV(i, 2)));
        convmfma_kernel<<<cgrid, 512, CONV_LDS_BYTES, stream>>>(v, SUM(SV(i, 2)), ode_n2w, ode_n2b,
            AP2, ST2, ode_b2, t0 + 0.05f, 0.1f, 1, z, u, kacc, SUM(SU(i, 2)));
        // k4
        convmfma_kernel<<<cgrid, 512, CONV_LDS_BYTES, stream>>>(u, SUM(SU(i, 2)), ode_n1w, ode_n1b,
            AP1, ST1, ode_b1, t0 + 0.1f, 0.f, 3, z, v, kacc, SUM(SV(i, 3)));
        convmfma_kernel<<<cgrid, 512, CONV_LDS_BYTES, stream>>>(v, SUM(SV(i, 3)), ode_n2w, ode_n2b,
            AP2, ST2, ode_b2, t0 + 0.1f, c6, 2, z, zb, kacc, SUM(ZS(i)));
    }

    // ---- head ----
    headgap_kernel<<<BB, 256, 0, stream>>>(z, head_nw, head_nb, pooled);
    headfc_kernel<<<3, 256, 0, stream>>>(pooled, head_W, head_b, (float*)d_out);
}